// Round 4
// baseline (3495.808 us; speedup 1.0000x reference)
//
#include <hip/hip_runtime.h>
#include <hip/hip_bf16.h>

// ---------------------------------------------------------------------------
// Problem constants (from reference setup_inputs)
// ---------------------------------------------------------------------------
#define N0 100000
#define E0C 1600000
#define N1 100000
#define E1C 1600000
#define GCONST 512
#define F0C 93
#define F1C 43
#define OC0 (F0C * 10)   // 930
#define OC1 (F1C * 10)   // 430
#define BN_EPS 1e-5f

// ---------------------------------------------------------------------------
// zero ints
// ---------------------------------------------------------------------------
__global__ __launch_bounds__(256) void zero_int_kernel(int* __restrict__ p, int n) {
    int i = blockIdx.x * 256 + threadIdx.x;
    if (i < n) p[i] = 0;
}

// ---------------------------------------------------------------------------
// graph boundary search: starts[g] = lower_bound(batch, g); starts[G] = N
// ---------------------------------------------------------------------------
__global__ __launch_bounds__(256) void find_starts_kernel(const int* __restrict__ batch,
                                                          int N, int G,
                                                          int* __restrict__ starts) {
    int g = blockIdx.x * 256 + threadIdx.x;
    if (g > G) return;
    if (g == G) { starts[G] = N; return; }
    int lo = 0, hi = N;
    while (lo < hi) {
        int mid = (lo + hi) >> 1;
        if (batch[mid] < g) lo = mid + 1; else hi = mid;
    }
    starts[g] = lo;
}

// ---------------------------------------------------------------------------
// CSR build: histogram of dst, scan, fill col with src per dst bucket
// ---------------------------------------------------------------------------
__global__ __launch_bounds__(256) void hist_kernel(const int* __restrict__ ei,
                                                   int E, int* __restrict__ deg) {
    int e = blockIdx.x * 256 + threadIdx.x;
    if (e >= E) return;
    atomicAdd(&deg[ei[E + e]], 1);   // dst row
}

__global__ __launch_bounds__(1024) void scan_kernel(const int* __restrict__ deg,
                                                    int N, int E,
                                                    int* __restrict__ rowptr,
                                                    int* __restrict__ cursor) {
    __shared__ int part[1024];
    int tid = threadIdx.x;
    int chunk = (N + 1023) / 1024;
    int s = tid * chunk;
    int e = s + chunk < N ? s + chunk : N;
    int sum = 0;
    for (int i = s; i < e; ++i) sum += deg[i];
    part[tid] = sum;
    __syncthreads();
    // inclusive Hillis-Steele scan over partials
    for (int off = 1; off < 1024; off <<= 1) {
        int add = (tid >= off) ? part[tid - off] : 0;
        __syncthreads();
        part[tid] += add;
        __syncthreads();
    }
    int run = part[tid] - sum;  // exclusive prefix of this chunk
    for (int i = s; i < e; ++i) {
        rowptr[i] = run;
        cursor[i] = run;
        run += deg[i];
    }
    if (tid == 1023) rowptr[N] = E;
}

__global__ __launch_bounds__(256) void fill_kernel(const int* __restrict__ ei,
                                                   int E,
                                                   int* __restrict__ cursor,
                                                   int* __restrict__ col) {
    int e = blockIdx.x * 256 + threadIdx.x;
    if (e >= E) return;
    int src = ei[e];
    int dst = ei[E + e];
    int pos = atomicAdd(&cursor[dst], 1);
    col[pos] = src;
}

// ---------------------------------------------------------------------------
// CSR gather-aggregate: t[i] = x[i] + sum_{j in row(i)} x[col[j]]
// block = (256/FPAD) nodes x FPAD feature-lanes; coalesced row reads.
// ---------------------------------------------------------------------------
template<int F, int FPAD>
__global__ __launch_bounds__(256) void gather_agg_kernel(float* __restrict__ t,
                                                         const float* __restrict__ x,
                                                         const int* __restrict__ rowptr,
                                                         const int* __restrict__ col,
                                                         int N) {
    constexpr int NPB = 256 / FPAD;
    int node = blockIdx.x * NPB + threadIdx.x / FPAD;
    int f = threadIdx.x % FPAD;
    if (node >= N || f >= F) return;
    int s = rowptr[node], e = rowptr[node + 1];
    float a0 = x[(size_t)node * F + f];
    float a1 = 0.f, a2 = 0.f, a3 = 0.f;
    int j = s;
    for (; j + 3 < e; j += 4) {
        int s0 = col[j], s1 = col[j + 1], s2 = col[j + 2], s3 = col[j + 3];
        a0 += x[(size_t)s0 * F + f];
        a1 += x[(size_t)s1 * F + f];
        a2 += x[(size_t)s2 * F + f];
        a3 += x[(size_t)s3 * F + f];
    }
    for (; j < e; ++j) a0 += x[(size_t)col[j] * F + f];
    t[(size_t)node * F + f] = (a0 + a1) + (a2 + a3);
}

// ---------------------------------------------------------------------------
// generic fp32 GEMM: C = A[MxK] @ B[KxN] + bias, optional relu.
// 64x64 tile, 256 threads, 4x4 register micro-tile, K-tile 16.
// ---------------------------------------------------------------------------
__global__ __launch_bounds__(256) void gemm_bias_kernel(const float* __restrict__ A,
                                                        const float* __restrict__ B,
                                                        const float* __restrict__ bias,
                                                        float* __restrict__ C,
                                                        int M, int N, int K, int relu) {
    __shared__ float As[16][64];
    __shared__ float Bs[16][64];
    int tid = threadIdx.x;
    int tx = tid & 15, ty = tid >> 4;
    int m0 = blockIdx.y * 64, n0 = blockIdx.x * 64;
    float acc[4][4] = {};
    for (int k0 = 0; k0 < K; k0 += 16) {
#pragma unroll
        for (int i = 0; i < 4; ++i) {
            int lin = tid + i * 256;
            int m = lin >> 4, k = lin & 15;
            int gm = m0 + m, gk = k0 + k;
            As[k][m] = (gm < M && gk < K) ? A[(size_t)gm * K + gk] : 0.f;
        }
#pragma unroll
        for (int i = 0; i < 4; ++i) {
            int lin = tid + i * 256;
            int n = lin & 63, k = lin >> 6;
            int gn = n0 + n, gk = k0 + k;
            Bs[k][n] = (gk < K && gn < N) ? B[(size_t)gk * N + gn] : 0.f;
        }
        __syncthreads();
#pragma unroll
        for (int k = 0; k < 16; ++k) {
            float a[4], b[4];
#pragma unroll
            for (int i = 0; i < 4; ++i) a[i] = As[k][ty * 4 + i];
#pragma unroll
            for (int j = 0; j < 4; ++j) b[j] = Bs[k][tx * 4 + j];
#pragma unroll
            for (int i = 0; i < 4; ++i)
#pragma unroll
                for (int j = 0; j < 4; ++j)
                    acc[i][j] = fmaf(a[i], b[j], acc[i][j]);
        }
        __syncthreads();
    }
#pragma unroll
    for (int i = 0; i < 4; ++i) {
        int gm = m0 + ty * 4 + i;
        if (gm >= M) continue;
#pragma unroll
        for (int j = 0; j < 4; ++j) {
            int gn = n0 + tx * 4 + j;
            if (gn >= N) continue;
            float v = acc[i][j] + bias[gn];
            if (relu) v = fmaxf(v, 0.f);
            C[(size_t)gm * N + gn] = v;
        }
    }
}

// ---------------------------------------------------------------------------
// fused conv2 matmul + relu + mean/max pool, node-chunked.
// thread = output column, block.y = graph.
// Process NB=8 nodes per chunk with KT=8 k-tile: load w[8] once, apply to all
// 8 nodes -> W L1 traffic cut 8x vs per-node reload (the compiler refuses to
// keep a 93-float W column register-resident; VGPR_Count stuck at 60 even
// with __launch_bounds__(256,2), so amortize instead of fighting it).
// t-row reads are wave-uniform (scalar/broadcast). FMA floor: 93x2cyc/node.
// pooled layout: [G][2*OC]  (mean | max)
// ---------------------------------------------------------------------------
template<int F>
__global__ __launch_bounds__(256) void conv2_pool_kernel(const float* __restrict__ t,
                                                         const float* __restrict__ W,
                                                         const float* __restrict__ bias,
                                                         const int* __restrict__ starts,
                                                         float* __restrict__ pooled,
                                                         int OC) {
    int col = blockIdx.x * 256 + threadIdx.x;
    if (col >= OC) return;  // no barriers below; early exit safe
    int g = blockIdx.y;
    float bb = bias[col];
    int s = starts[g], e = starts[g + 1];
    float sum = 0.f, mx = 0.f;

    constexpr int KT = 8;
    constexpr int NKT = F / KT;        // full k-tiles
    constexpr int KREM = F - NKT * KT; // tail k (5 for F=93, 3 for F=43)
    constexpr int NB = 8;

    int n = s;
    for (; n + NB <= e; n += NB) {
        float acc[NB];
#pragma unroll
        for (int i = 0; i < NB; ++i) acc[i] = 0.f;
        const float* __restrict__ tb = t + (size_t)n * F;
#pragma unroll
        for (int c = 0; c < NKT; ++c) {
            int k0 = c * KT;
            float w[KT];
#pragma unroll
            for (int kk = 0; kk < KT; ++kk) w[kk] = W[(size_t)(k0 + kk) * OC + col];
#pragma unroll
            for (int i = 0; i < NB; ++i) {
                const float* __restrict__ tr = tb + i * F + k0;
#pragma unroll
                for (int kk = 0; kk < KT; ++kk)
                    acc[i] = fmaf(w[kk], tr[kk], acc[i]);
            }
        }
        if (KREM > 0) {
            int k0 = NKT * KT;
            float w[KREM > 0 ? KREM : 1];
#pragma unroll
            for (int kk = 0; kk < KREM; ++kk) w[kk] = W[(size_t)(k0 + kk) * OC + col];
#pragma unroll
            for (int i = 0; i < NB; ++i) {
                const float* __restrict__ tr = tb + i * F + k0;
#pragma unroll
                for (int kk = 0; kk < KREM; ++kk)
                    acc[i] = fmaf(w[kk], tr[kk], acc[i]);
            }
        }
#pragma unroll
        for (int i = 0; i < NB; ++i) {
            float o = fmaxf(bb + acc[i], 0.f);
            sum += o;
            mx = fmaxf(mx, o);
        }
    }
    // node tail (< NB nodes)
    for (; n < e; ++n) {
        const float* __restrict__ tr = t + (size_t)n * F;
        float a0 = 0.f;
#pragma unroll
        for (int k = 0; k < F; ++k) a0 = fmaf(W[(size_t)k * OC + col], tr[k], a0);
        float o = fmaxf(bb + a0, 0.f);
        sum += o;
        mx = fmaxf(mx, o);
    }
    int cnt = e - s;
    float mean = sum / (float)(cnt > 0 ? cnt : 1);
    size_t base = (size_t)g * (size_t)(2 * OC);
    pooled[base + col] = mean;
    pooled[base + OC + col] = mx;
}

// ---------------------------------------------------------------------------
// batchnorm stats + apply
// ---------------------------------------------------------------------------
__global__ __launch_bounds__(256) void bn_stats_kernel(const float* __restrict__ p,
                                                       int rows, int cols,
                                                       float* __restrict__ mean,
                                                       float* __restrict__ inv) {
    int c = blockIdx.x;
    float s = 0.f, s2 = 0.f;
    for (int r = threadIdx.x; r < rows; r += 256) {
        float v = p[(size_t)r * cols + c];
        s += v;
        s2 += v * v;
    }
    __shared__ float ls[256], ls2[256];
    ls[threadIdx.x] = s;
    ls2[threadIdx.x] = s2;
    __syncthreads();
    for (int st = 128; st > 0; st >>= 1) {
        if (threadIdx.x < st) {
            ls[threadIdx.x] += ls[threadIdx.x + st];
            ls2[threadIdx.x] += ls2[threadIdx.x + st];
        }
        __syncthreads();
    }
    if (threadIdx.x == 0) {
        float m = ls[0] / (float)rows;
        float var = ls2[0] / (float)rows - m * m;
        mean[c] = m;
        inv[c] = 1.f / sqrtf(var + BN_EPS);
    }
}

__global__ __launch_bounds__(256) void bn_apply_kernel(const float* __restrict__ p,
                                                       const float* __restrict__ gamma,
                                                       const float* __restrict__ beta,
                                                       const float* __restrict__ mean,
                                                       const float* __restrict__ inv,
                                                       float* __restrict__ outp,
                                                       int total, int cols) {
    int i = blockIdx.x * 256 + threadIdx.x;
    if (i >= total) return;
    int c = i & (cols - 1);  // cols = 512 (pow2)
    outp[i] = gamma[c] * (p[i] - mean[c]) * inv[c] + beta[c];
}

// ---------------------------------------------------------------------------
// launch
// ---------------------------------------------------------------------------
static inline int ceildiv(int a, int b) { return (a + b - 1) / b; }

extern "C" void kernel_launch(void* const* d_in, const int* in_sizes, int n_in,
                              void* d_out, int out_size, void* d_ws, size_t ws_size,
                              hipStream_t stream) {
    const float* x0   = (const float*)d_in[0];
    const float* x1   = (const float*)d_in[1];
    const int*   ei0  = (const int*)d_in[2];
    const int*   ei1  = (const int*)d_in[3];
    const int*   bat0 = (const int*)d_in[4];
    const int*   bat1 = (const int*)d_in[5];
    const float* w_c1 = (const float*)d_in[6];
    const float* b_c1 = (const float*)d_in[7];
    const float* w_c2 = (const float*)d_in[8];
    const float* b_c2 = (const float*)d_in[9];
    const float* w_c3 = (const float*)d_in[10];
    const float* b_c3 = (const float*)d_in[11];
    const float* w_c4 = (const float*)d_in[12];
    const float* b_c4 = (const float*)d_in[13];
    const float* g0_w1 = (const float*)d_in[14];
    const float* g0_b1 = (const float*)d_in[15];
    const float* g0_w2 = (const float*)d_in[16];
    const float* g0_b2 = (const float*)d_in[17];
    const float* g0_bn_g = (const float*)d_in[18];
    const float* g0_bn_b = (const float*)d_in[19];
    const float* g1_w1 = (const float*)d_in[20];
    const float* g1_b1 = (const float*)d_in[21];
    const float* g1_w2 = (const float*)d_in[22];
    const float* g1_b2 = (const float*)d_in[23];
    const float* g1_bn_g = (const float*)d_in[24];
    const float* g1_bn_b = (const float*)d_in[25];
    const float* f0_w1 = (const float*)d_in[26];
    const float* f0_b1 = (const float*)d_in[27];
    const float* f0_w2 = (const float*)d_in[28];
    const float* f0_b2 = (const float*)d_in[29];
    const float* f1_w1 = (const float*)d_in[30];
    const float* f1_b1 = (const float*)d_in[31];
    const float* f1_w2 = (const float*)d_in[32];
    const float* f1_b2 = (const float*)d_in[33];

    float* out = (float*)d_out;
    // d_out layout: z [512*2] | x_g_0 [512*512] | x_g_1 [512*512] | z1 [512*2]
    float* out_z   = out;
    float* out_xg0 = out + 1024;
    float* out_xg1 = out + 1024 + 262144;
    float* out_z1  = out + 1024 + 262144 + 262144;

    // workspace carve (floats)
    float* ws = (float*)d_ws;
    size_t off = 0;
    auto alloc = [&](size_t n) { float* p = ws + off; off += n; return p; };
    float* t  = alloc((size_t)N0 * F0C);   // 9.3M
    float* y1 = alloc((size_t)N0 * F0C);   // 9.3M
    // Union region C: CSR (graph phase) aliases MLP temps (dense phase).
    // CSR is dead before conv2_pool writes pooled -> safe.
    size_t csr_floats = (size_t)N0 + (N0 + 1) + N0 + E0C;        // 1.90M
    size_t mlp_floats = (size_t)GCONST * 2 * OC0 + (size_t)GCONST * 2 * OC1 +
                        (size_t)GCONST * 1024 + (size_t)GCONST * 512 +
                        (size_t)GCONST * 256;                     // 2.31M
    float* regionC = alloc(csr_floats > mlp_floats ? csr_floats : mlp_floats);
    int* deg    = (int*)regionC;
    int* rowptr = deg + N0;
    int* cursor = rowptr + (N0 + 1);
    int* colb   = cursor + N0;
    float* pooled0 = regionC;
    float* pooled1 = pooled0 + (size_t)GCONST * 2 * OC0;
    float* m1      = pooled1 + (size_t)GCONST * 2 * OC1;
    float* pbn     = m1 + (size_t)GCONST * 1024;
    float* hbuf    = pbn + (size_t)GCONST * 512;
    float* meanb   = alloc(512);
    float* invb    = alloc(512);
    int*   starts0 = (int*)alloc(520);
    int*   starts1 = (int*)alloc(520);

    const int G = GCONST;

    // =========================== branch 0 (F=93) ===========================
    {
        const int N = N0, F = F0C, E = E0C, OC = OC0;
        find_starts_kernel<<<3, 256, 0, stream>>>(bat0, N, G, starts0);
        // --- CSR build (amortized over both conv layers) ---
        zero_int_kernel<<<ceildiv(N, 256), 256, 0, stream>>>(deg, N);
        hist_kernel<<<ceildiv(E, 256), 256, 0, stream>>>(ei0, E, deg);
        scan_kernel<<<1, 1024, 0, stream>>>(deg, N, E, rowptr, cursor);
        fill_kernel<<<ceildiv(E, 256), 256, 0, stream>>>(ei0, E, cursor, colb);
        // --- conv1: t = x + agg(x); y1 = relu(t @ w_c1 + b_c1) ---
        gather_agg_kernel<F0C, 128><<<ceildiv(N, 2), 256, 0, stream>>>(t, x0, rowptr, colb, N);
        gemm_bias_kernel<<<dim3(ceildiv(F, 64), ceildiv(N, 64)), 256, 0, stream>>>(
            t, w_c1, b_c1, y1, N, F, F, 1);
        // --- conv2 aggregate: t = y1 + agg(y1) ---
        gather_agg_kernel<F0C, 128><<<ceildiv(N, 2), 256, 0, stream>>>(t, y1, rowptr, colb, N);
        // --- fused conv2 matmul + relu + mean/max pool (CSR dead from here) ---
        conv2_pool_kernel<F0C><<<dim3(ceildiv(OC, 256), G), 256, 0, stream>>>(
            t, w_c2, b_c2, starts0, pooled0, OC);
        // --- MLP ---
        gemm_bias_kernel<<<dim3(1024 / 64, G / 64), 256, 0, stream>>>(
            pooled0, g0_w1, g0_b1, m1, G, 1024, 2 * OC, 1);
        gemm_bias_kernel<<<dim3(512 / 64, G / 64), 256, 0, stream>>>(
            m1, g0_w2, g0_b2, pbn, G, 512, 1024, 0);
        bn_stats_kernel<<<512, 256, 0, stream>>>(pbn, G, 512, meanb, invb);
        bn_apply_kernel<<<ceildiv(G * 512, 256), 256, 0, stream>>>(
            pbn, g0_bn_g, g0_bn_b, meanb, invb, out_xg0, G * 512, 512);
        // --- head ---
        gemm_bias_kernel<<<dim3(256 / 64, G / 64), 256, 0, stream>>>(
            out_xg0, f0_w1, f0_b1, hbuf, G, 256, 512, 1);
        gemm_bias_kernel<<<dim3(1, G / 64), 256, 0, stream>>>(
            hbuf, f0_w2, f0_b2, out_z, G, 2, 256, 0);
    }

    // =========================== branch 1 (F=43) ===========================
    {
        const int N = N1, F = F1C, E = E1C, OC = OC1;
        find_starts_kernel<<<3, 256, 0, stream>>>(bat1, N, G, starts1);
        zero_int_kernel<<<ceildiv(N, 256), 256, 0, stream>>>(deg, N);
        hist_kernel<<<ceildiv(E, 256), 256, 0, stream>>>(ei1, E, deg);
        scan_kernel<<<1, 1024, 0, stream>>>(deg, N, E, rowptr, cursor);
        fill_kernel<<<ceildiv(E, 256), 256, 0, stream>>>(ei1, E, cursor, colb);
        gather_agg_kernel<F1C, 64><<<ceildiv(N, 4), 256, 0, stream>>>(t, x1, rowptr, colb, N);
        gemm_bias_kernel<<<dim3(ceildiv(F, 64), ceildiv(N, 64)), 256, 0, stream>>>(
            t, w_c3, b_c3, y1, N, F, F, 1);
        gather_agg_kernel<F1C, 64><<<ceildiv(N, 4), 256, 0, stream>>>(t, y1, rowptr, colb, N);
        conv2_pool_kernel<F1C><<<dim3(ceildiv(OC, 256), G), 256, 0, stream>>>(
            t, w_c4, b_c4, starts1, pooled1, OC);
        gemm_bias_kernel<<<dim3(1024 / 64, G / 64), 256, 0, stream>>>(
            pooled1, g1_w1, g1_b1, m1, G, 1024, 2 * OC, 1);
        gemm_bias_kernel<<<dim3(512 / 64, G / 64), 256, 0, stream>>>(
            m1, g1_w2, g1_b2, pbn, G, 512, 1024, 0);
        bn_stats_kernel<<<512, 256, 0, stream>>>(pbn, G, 512, meanb, invb);
        bn_apply_kernel<<<ceildiv(G * 512, 256), 256, 0, stream>>>(
            pbn, g1_bn_g, g1_bn_b, meanb, invb, out_xg1, G * 512, 512);
        gemm_bias_kernel<<<dim3(256 / 64, G / 64), 256, 0, stream>>>(
            out_xg1, f1_w1, f1_b1, hbuf, G, 256, 512, 1);
        gemm_bias_kernel<<<dim3(1, G / 64), 256, 0, stream>>>(
            hbuf, f1_w2, f1_b2, out_z1, G, 2, 256, 0);
    }
}

// Round 5
// 3286.710 us; speedup vs baseline: 1.0636x; 1.0636x over previous
//
#include <hip/hip_runtime.h>
#include <hip/hip_bf16.h>

// ---------------------------------------------------------------------------
// Problem constants (from reference setup_inputs)
// ---------------------------------------------------------------------------
#define N0 100000
#define E0C 1600000
#define N1 100000
#define E1C 1600000
#define GCONST 512
#define F0C 93
#define F1C 43
#define OC0 (F0C * 10)   // 930
#define OC1 (F1C * 10)   // 430
#define BN_EPS 1e-5f

// ---------------------------------------------------------------------------
// zero ints
// ---------------------------------------------------------------------------
__global__ __launch_bounds__(256) void zero_int_kernel(int* __restrict__ p, int n) {
    int i = blockIdx.x * 256 + threadIdx.x;
    if (i < n) p[i] = 0;
}

// ---------------------------------------------------------------------------
// graph boundary search: starts[g] = lower_bound(batch, g); starts[G] = N
// ---------------------------------------------------------------------------
__global__ __launch_bounds__(256) void find_starts_kernel(const int* __restrict__ batch,
                                                          int N, int G,
                                                          int* __restrict__ starts) {
    int g = blockIdx.x * 256 + threadIdx.x;
    if (g > G) return;
    if (g == G) { starts[G] = N; return; }
    int lo = 0, hi = N;
    while (lo < hi) {
        int mid = (lo + hi) >> 1;
        if (batch[mid] < g) lo = mid + 1; else hi = mid;
    }
    starts[g] = lo;
}

// ---------------------------------------------------------------------------
// CSR build: histogram of dst, scan, fill col with src per dst bucket
// ---------------------------------------------------------------------------
__global__ __launch_bounds__(256) void hist_kernel(const int* __restrict__ ei,
                                                   int E, int* __restrict__ deg) {
    int e = blockIdx.x * 256 + threadIdx.x;
    if (e >= E) return;
    atomicAdd(&deg[ei[E + e]], 1);   // dst row
}

__global__ __launch_bounds__(1024) void scan_kernel(const int* __restrict__ deg,
                                                    int N, int E,
                                                    int* __restrict__ rowptr,
                                                    int* __restrict__ cursor) {
    __shared__ int part[1024];
    int tid = threadIdx.x;
    int chunk = (N + 1023) / 1024;
    int s = tid * chunk;
    int e = s + chunk < N ? s + chunk : N;
    int sum = 0;
    for (int i = s; i < e; ++i) sum += deg[i];
    part[tid] = sum;
    __syncthreads();
    // inclusive Hillis-Steele scan over partials
    for (int off = 1; off < 1024; off <<= 1) {
        int add = (tid >= off) ? part[tid - off] : 0;
        __syncthreads();
        part[tid] += add;
        __syncthreads();
    }
    int run = part[tid] - sum;  // exclusive prefix of this chunk
    for (int i = s; i < e; ++i) {
        rowptr[i] = run;
        cursor[i] = run;
        run += deg[i];
    }
    if (tid == 1023) rowptr[N] = E;
}

__global__ __launch_bounds__(256) void fill_kernel(const int* __restrict__ ei,
                                                   int E,
                                                   int* __restrict__ cursor,
                                                   int* __restrict__ col) {
    int e = blockIdx.x * 256 + threadIdx.x;
    if (e >= E) return;
    int src = ei[e];
    int dst = ei[E + e];
    int pos = atomicAdd(&cursor[dst], 1);
    col[pos] = src;
}

// ---------------------------------------------------------------------------
// CSR gather-aggregate: t[i] = x[i] + sum_{j in row(i)} x[col[j]]
// block = (256/FPAD) nodes x FPAD feature-lanes; coalesced row reads.
// ---------------------------------------------------------------------------
template<int F, int FPAD>
__global__ __launch_bounds__(256) void gather_agg_kernel(float* __restrict__ t,
                                                         const float* __restrict__ x,
                                                         const int* __restrict__ rowptr,
                                                         const int* __restrict__ col,
                                                         int N) {
    constexpr int NPB = 256 / FPAD;
    int node = blockIdx.x * NPB + threadIdx.x / FPAD;
    int f = threadIdx.x % FPAD;
    if (node >= N || f >= F) return;
    int s = rowptr[node], e = rowptr[node + 1];
    float a0 = x[(size_t)node * F + f];
    float a1 = 0.f, a2 = 0.f, a3 = 0.f;
    int j = s;
    for (; j + 3 < e; j += 4) {
        int s0 = col[j], s1 = col[j + 1], s2 = col[j + 2], s3 = col[j + 3];
        a0 += x[(size_t)s0 * F + f];
        a1 += x[(size_t)s1 * F + f];
        a2 += x[(size_t)s2 * F + f];
        a3 += x[(size_t)s3 * F + f];
    }
    for (; j < e; ++j) a0 += x[(size_t)col[j] * F + f];
    t[(size_t)node * F + f] = (a0 + a1) + (a2 + a3);
}

// ---------------------------------------------------------------------------
// generic fp32 GEMM: C = A[MxK] @ B[KxN] + bias, optional relu.
// 64x64 tile, 256 threads, 4x4 register micro-tile, K-tile 16.
// ---------------------------------------------------------------------------
__global__ __launch_bounds__(256) void gemm_bias_kernel(const float* __restrict__ A,
                                                        const float* __restrict__ B,
                                                        const float* __restrict__ bias,
                                                        float* __restrict__ C,
                                                        int M, int N, int K, int relu) {
    __shared__ float As[16][64];
    __shared__ float Bs[16][64];
    int tid = threadIdx.x;
    int tx = tid & 15, ty = tid >> 4;
    int m0 = blockIdx.y * 64, n0 = blockIdx.x * 64;
    float acc[4][4] = {};
    for (int k0 = 0; k0 < K; k0 += 16) {
#pragma unroll
        for (int i = 0; i < 4; ++i) {
            int lin = tid + i * 256;
            int m = lin >> 4, k = lin & 15;
            int gm = m0 + m, gk = k0 + k;
            As[k][m] = (gm < M && gk < K) ? A[(size_t)gm * K + gk] : 0.f;
        }
#pragma unroll
        for (int i = 0; i < 4; ++i) {
            int lin = tid + i * 256;
            int n = lin & 63, k = lin >> 6;
            int gn = n0 + n, gk = k0 + k;
            Bs[k][n] = (gk < K && gn < N) ? B[(size_t)gk * N + gn] : 0.f;
        }
        __syncthreads();
#pragma unroll
        for (int k = 0; k < 16; ++k) {
            float a[4], b[4];
#pragma unroll
            for (int i = 0; i < 4; ++i) a[i] = As[k][ty * 4 + i];
#pragma unroll
            for (int j = 0; j < 4; ++j) b[j] = Bs[k][tx * 4 + j];
#pragma unroll
            for (int i = 0; i < 4; ++i)
#pragma unroll
                for (int j = 0; j < 4; ++j)
                    acc[i][j] = fmaf(a[i], b[j], acc[i][j]);
        }
        __syncthreads();
    }
#pragma unroll
    for (int i = 0; i < 4; ++i) {
        int gm = m0 + ty * 4 + i;
        if (gm >= M) continue;
#pragma unroll
        for (int j = 0; j < 4; ++j) {
            int gn = n0 + tx * 4 + j;
            if (gn >= N) continue;
            float v = acc[i][j] + bias[gn];
            if (relu) v = fmaxf(v, 0.f);
            C[(size_t)gm * N + gn] = v;
        }
    }
}

// ---------------------------------------------------------------------------
// conv2 + relu + mean/max pool as an LDS-tiled GEMM with fused segment pool.
// block = (64-col tile, graph). W tile (F x 64) staged in LDS ONCE per block;
// t staged in 64-node chunks TRANSPOSED (k-major, stride 68 -> conflict-free
// b128 reads; 16B-aligned). Thread = 4 nodes x 4 cols micro-tile: per k,
// 2x ds_read_b128 feed 16 FMAs -> compute-bound (prev structures were
// L1-load-bound; compiler refused register-resident W, VGPR stuck at 56-60).
// Pool accumulated in registers with node-validity mask, LDS tree-reduce
// across the 16 node-groups at the end. pooled layout: [G][2*OC] (mean|max).
// ---------------------------------------------------------------------------
template<int F>
__global__ __launch_bounds__(256) void conv2_pool_gemm(const float* __restrict__ t,
                                                       const float* __restrict__ W,
                                                       const float* __restrict__ bias,
                                                       const int* __restrict__ starts,
                                                       float* __restrict__ pooled,
                                                       int OC) {
    constexpr int TS = 68;                 // t_lds k-stride (mult of 4, !mult of 32)
    __shared__ float w_lds[F * 64];        // k-major: w_lds[k*64 + c]
    __shared__ float t_lds[F * TS];        // k-major: t_lds[k*TS + n]
    int tid = threadIdx.x;
    int tx = tid & 15, ty = tid >> 4;
    int g = blockIdx.y;
    int c0 = blockIdx.x * 64;

    // stage W tile once (coalesced reads, sequential LDS writes)
    for (int idx = tid; idx < F * 64; idx += 256) {
        int k = idx >> 6, c = idx & 63;
        int col = c0 + c;
        w_lds[idx] = (col < OC) ? W[(size_t)k * OC + col] : 0.f;
    }
    float bb[4];
#pragma unroll
    for (int j = 0; j < 4; ++j) {
        int col = c0 + tx * 4 + j;
        bb[j] = (col < OC) ? bias[col] : 0.f;
    }

    int s = starts[g], e = starts[g + 1];
    float sum[4] = {0.f, 0.f, 0.f, 0.f};
    float mx[4]  = {0.f, 0.f, 0.f, 0.f};   // relu outputs >= 0, so 0 is safe

    for (int ns = s; ns < e; ns += 64) {
        __syncthreads();   // protect t_lds from prev iter; covers W staging on iter 0
        // stage 64 nodes of t, transposed (coalesced global reads)
        for (int idx = tid; idx < 64 * F; idx += 256) {
            int n = idx / F, k = idx - n * F;
            int row = ns + n;
            t_lds[k * TS + n] = (row < e) ? t[(size_t)row * F + k] : 0.f;
        }
        __syncthreads();

        float acc[4][4] = {};
#pragma unroll 4
        for (int k = 0; k < F; ++k) {
            float4 a = *(const float4*)&t_lds[k * TS + ty * 4];
            float4 b = *(const float4*)&w_lds[k * 64 + tx * 4];
            acc[0][0] = fmaf(a.x, b.x, acc[0][0]);
            acc[0][1] = fmaf(a.x, b.y, acc[0][1]);
            acc[0][2] = fmaf(a.x, b.z, acc[0][2]);
            acc[0][3] = fmaf(a.x, b.w, acc[0][3]);
            acc[1][0] = fmaf(a.y, b.x, acc[1][0]);
            acc[1][1] = fmaf(a.y, b.y, acc[1][1]);
            acc[1][2] = fmaf(a.y, b.z, acc[1][2]);
            acc[1][3] = fmaf(a.y, b.w, acc[1][3]);
            acc[2][0] = fmaf(a.z, b.x, acc[2][0]);
            acc[2][1] = fmaf(a.z, b.y, acc[2][1]);
            acc[2][2] = fmaf(a.z, b.z, acc[2][2]);
            acc[2][3] = fmaf(a.z, b.w, acc[2][3]);
            acc[3][0] = fmaf(a.w, b.x, acc[3][0]);
            acc[3][1] = fmaf(a.w, b.y, acc[3][1]);
            acc[3][2] = fmaf(a.w, b.z, acc[3][2]);
            acc[3][3] = fmaf(a.w, b.w, acc[3][3]);
        }
        // fused relu + masked pool accumulation
#pragma unroll
        for (int i = 0; i < 4; ++i) {
            bool valid = (ns + ty * 4 + i) < e;
#pragma unroll
            for (int j = 0; j < 4; ++j) {
                float o = fmaxf(acc[i][j] + bb[j], 0.f);
                if (valid) {
                    sum[j] += o;
                    mx[j] = fmaxf(mx[j], o);
                }
            }
        }
    }

    // cross-ty reduction (16 node-groups) via w_lds scratch (>= 2048 floats)
    __syncthreads();
    float* red_s = w_lds;          // [16][64]
    float* red_m = w_lds + 1024;   // [16][64]
#pragma unroll
    for (int j = 0; j < 4; ++j) {
        red_s[ty * 64 + tx * 4 + j] = sum[j];
        red_m[ty * 64 + tx * 4 + j] = mx[j];
    }
    __syncthreads();
    for (int st = 8; st >= 1; st >>= 1) {
        if (ty < st) {
#pragma unroll
            for (int j = 0; j < 4; ++j) {
                int a = ty * 64 + tx * 4 + j;
                int b = (ty + st) * 64 + tx * 4 + j;
                red_s[a] += red_s[b];
                red_m[a] = fmaxf(red_m[a], red_m[b]);
            }
        }
        __syncthreads();
    }
    if (ty == 0) {
        int cnt = e - s;
        float rc = 1.f / (float)(cnt > 0 ? cnt : 1);
        size_t base = (size_t)g * (size_t)(2 * OC);
#pragma unroll
        for (int j = 0; j < 4; ++j) {
            int col = c0 + tx * 4 + j;
            if (col < OC) {
                pooled[base + col] = red_s[tx * 4 + j] * rc;
                pooled[base + OC + col] = red_m[tx * 4 + j];
            }
        }
    }
}

// ---------------------------------------------------------------------------
// batchnorm stats + apply
// ---------------------------------------------------------------------------
__global__ __launch_bounds__(256) void bn_stats_kernel(const float* __restrict__ p,
                                                       int rows, int cols,
                                                       float* __restrict__ mean,
                                                       float* __restrict__ inv) {
    int c = blockIdx.x;
    float s = 0.f, s2 = 0.f;
    for (int r = threadIdx.x; r < rows; r += 256) {
        float v = p[(size_t)r * cols + c];
        s += v;
        s2 += v * v;
    }
    __shared__ float ls[256], ls2[256];
    ls[threadIdx.x] = s;
    ls2[threadIdx.x] = s2;
    __syncthreads();
    for (int st = 128; st > 0; st >>= 1) {
        if (threadIdx.x < st) {
            ls[threadIdx.x] += ls[threadIdx.x + st];
            ls2[threadIdx.x] += ls2[threadIdx.x + st];
        }
        __syncthreads();
    }
    if (threadIdx.x == 0) {
        float m = ls[0] / (float)rows;
        float var = ls2[0] / (float)rows - m * m;
        mean[c] = m;
        inv[c] = 1.f / sqrtf(var + BN_EPS);
    }
}

__global__ __launch_bounds__(256) void bn_apply_kernel(const float* __restrict__ p,
                                                       const float* __restrict__ gamma,
                                                       const float* __restrict__ beta,
                                                       const float* __restrict__ mean,
                                                       const float* __restrict__ inv,
                                                       float* __restrict__ outp,
                                                       int total, int cols) {
    int i = blockIdx.x * 256 + threadIdx.x;
    if (i >= total) return;
    int c = i & (cols - 1);  // cols = 512 (pow2)
    outp[i] = gamma[c] * (p[i] - mean[c]) * inv[c] + beta[c];
}

// ---------------------------------------------------------------------------
// launch
// ---------------------------------------------------------------------------
static inline int ceildiv(int a, int b) { return (a + b - 1) / b; }

extern "C" void kernel_launch(void* const* d_in, const int* in_sizes, int n_in,
                              void* d_out, int out_size, void* d_ws, size_t ws_size,
                              hipStream_t stream) {
    const float* x0   = (const float*)d_in[0];
    const float* x1   = (const float*)d_in[1];
    const int*   ei0  = (const int*)d_in[2];
    const int*   ei1  = (const int*)d_in[3];
    const int*   bat0 = (const int*)d_in[4];
    const int*   bat1 = (const int*)d_in[5];
    const float* w_c1 = (const float*)d_in[6];
    const float* b_c1 = (const float*)d_in[7];
    const float* w_c2 = (const float*)d_in[8];
    const float* b_c2 = (const float*)d_in[9];
    const float* w_c3 = (const float*)d_in[10];
    const float* b_c3 = (const float*)d_in[11];
    const float* w_c4 = (const float*)d_in[12];
    const float* b_c4 = (const float*)d_in[13];
    const float* g0_w1 = (const float*)d_in[14];
    const float* g0_b1 = (const float*)d_in[15];
    const float* g0_w2 = (const float*)d_in[16];
    const float* g0_b2 = (const float*)d_in[17];
    const float* g0_bn_g = (const float*)d_in[18];
    const float* g0_bn_b = (const float*)d_in[19];
    const float* g1_w1 = (const float*)d_in[20];
    const float* g1_b1 = (const float*)d_in[21];
    const float* g1_w2 = (const float*)d_in[22];
    const float* g1_b2 = (const float*)d_in[23];
    const float* g1_bn_g = (const float*)d_in[24];
    const float* g1_bn_b = (const float*)d_in[25];
    const float* f0_w1 = (const float*)d_in[26];
    const float* f0_b1 = (const float*)d_in[27];
    const float* f0_w2 = (const float*)d_in[28];
    const float* f0_b2 = (const float*)d_in[29];
    const float* f1_w1 = (const float*)d_in[30];
    const float* f1_b1 = (const float*)d_in[31];
    const float* f1_w2 = (const float*)d_in[32];
    const float* f1_b2 = (const float*)d_in[33];

    float* out = (float*)d_out;
    // d_out layout: z [512*2] | x_g_0 [512*512] | x_g_1 [512*512] | z1 [512*2]
    float* out_z   = out;
    float* out_xg0 = out + 1024;
    float* out_xg1 = out + 1024 + 262144;
    float* out_z1  = out + 1024 + 262144 + 262144;

    // workspace carve (floats)
    float* ws = (float*)d_ws;
    size_t off = 0;
    auto alloc = [&](size_t n) { float* p = ws + off; off += n; return p; };
    float* t  = alloc((size_t)N0 * F0C);   // 9.3M
    float* y1 = alloc((size_t)N0 * F0C);   // 9.3M
    // Union region C: CSR (graph phase) aliases MLP temps (dense phase).
    // CSR is dead before conv2_pool_gemm writes pooled -> safe.
    size_t csr_floats = (size_t)N0 + (N0 + 1) + N0 + E0C;        // 1.90M
    size_t mlp_floats = (size_t)GCONST * 2 * OC0 + (size_t)GCONST * 2 * OC1 +
                        (size_t)GCONST * 1024 + (size_t)GCONST * 512 +
                        (size_t)GCONST * 256;                     // 2.31M
    float* regionC = alloc(csr_floats > mlp_floats ? csr_floats : mlp_floats);
    int* deg    = (int*)regionC;
    int* rowptr = deg + N0;
    int* cursor = rowptr + (N0 + 1);
    int* colb   = cursor + N0;
    float* pooled0 = regionC;
    float* pooled1 = pooled0 + (size_t)GCONST * 2 * OC0;
    float* m1      = pooled1 + (size_t)GCONST * 2 * OC1;
    float* pbn     = m1 + (size_t)GCONST * 1024;
    float* hbuf    = pbn + (size_t)GCONST * 512;
    float* meanb   = alloc(512);
    float* invb    = alloc(512);
    int*   starts0 = (int*)alloc(520);
    int*   starts1 = (int*)alloc(520);

    const int G = GCONST;

    // =========================== branch 0 (F=93) ===========================
    {
        const int N = N0, F = F0C, E = E0C, OC = OC0;
        find_starts_kernel<<<3, 256, 0, stream>>>(bat0, N, G, starts0);
        // --- CSR build (amortized over both conv layers) ---
        zero_int_kernel<<<ceildiv(N, 256), 256, 0, stream>>>(deg, N);
        hist_kernel<<<ceildiv(E, 256), 256, 0, stream>>>(ei0, E, deg);
        scan_kernel<<<1, 1024, 0, stream>>>(deg, N, E, rowptr, cursor);
        fill_kernel<<<ceildiv(E, 256), 256, 0, stream>>>(ei0, E, cursor, colb);
        // --- conv1: t = x + agg(x); y1 = relu(t @ w_c1 + b_c1) ---
        gather_agg_kernel<F0C, 128><<<ceildiv(N, 2), 256, 0, stream>>>(t, x0, rowptr, colb, N);
        gemm_bias_kernel<<<dim3(ceildiv(F, 64), ceildiv(N, 64)), 256, 0, stream>>>(
            t, w_c1, b_c1, y1, N, F, F, 1);
        // --- conv2 aggregate: t = y1 + agg(y1) ---
        gather_agg_kernel<F0C, 128><<<ceildiv(N, 2), 256, 0, stream>>>(t, y1, rowptr, colb, N);
        // --- fused conv2 GEMM + relu + mean/max pool (CSR dead from here) ---
        conv2_pool_gemm<F0C><<<dim3(ceildiv(OC, 64), G), 256, 0, stream>>>(
            t, w_c2, b_c2, starts0, pooled0, OC);
        // --- MLP ---
        gemm_bias_kernel<<<dim3(1024 / 64, G / 64), 256, 0, stream>>>(
            pooled0, g0_w1, g0_b1, m1, G, 1024, 2 * OC, 1);
        gemm_bias_kernel<<<dim3(512 / 64, G / 64), 256, 0, stream>>>(
            m1, g0_w2, g0_b2, pbn, G, 512, 1024, 0);
        bn_stats_kernel<<<512, 256, 0, stream>>>(pbn, G, 512, meanb, invb);
        bn_apply_kernel<<<ceildiv(G * 512, 256), 256, 0, stream>>>(
            pbn, g0_bn_g, g0_bn_b, meanb, invb, out_xg0, G * 512, 512);
        // --- head ---
        gemm_bias_kernel<<<dim3(256 / 64, G / 64), 256, 0, stream>>>(
            out_xg0, f0_w1, f0_b1, hbuf, G, 256, 512, 1);
        gemm_bias_kernel<<<dim3(1, G / 64), 256, 0, stream>>>(
            hbuf, f0_w2, f0_b2, out_z, G, 2, 256, 0);
    }

    // =========================== branch 1 (F=43) ===========================
    {
        const int N = N1, F = F1C, E = E1C, OC = OC1;
        find_starts_kernel<<<3, 256, 0, stream>>>(bat1, N, G, starts1);
        zero_int_kernel<<<ceildiv(N, 256), 256, 0, stream>>>(deg, N);
        hist_kernel<<<ceildiv(E, 256), 256, 0, stream>>>(ei1, E, deg);
        scan_kernel<<<1, 1024, 0, stream>>>(deg, N, E, rowptr, cursor);
        fill_kernel<<<ceildiv(E, 256), 256, 0, stream>>>(ei1, E, cursor, colb);
        gather_agg_kernel<F1C, 64><<<ceildiv(N, 4), 256, 0, stream>>>(t, x1, rowptr, colb, N);
        gemm_bias_kernel<<<dim3(ceildiv(F, 64), ceildiv(N, 64)), 256, 0, stream>>>(
            t, w_c3, b_c3, y1, N, F, F, 1);
        gather_agg_kernel<F1C, 64><<<ceildiv(N, 4), 256, 0, stream>>>(t, y1, rowptr, colb, N);
        conv2_pool_gemm<F1C><<<dim3(ceildiv(OC, 64), G), 256, 0, stream>>>(
            t, w_c4, b_c4, starts1, pooled1, OC);
        gemm_bias_kernel<<<dim3(1024 / 64, G / 64), 256, 0, stream>>>(
            pooled1, g1_w1, g1_b1, m1, G, 1024, 2 * OC, 1);
        gemm_bias_kernel<<<dim3(512 / 64, G / 64), 256, 0, stream>>>(
            m1, g1_w2, g1_b2, pbn, G, 512, 1024, 0);
        bn_stats_kernel<<<512, 256, 0, stream>>>(pbn, G, 512, meanb, invb);
        bn_apply_kernel<<<ceildiv(G * 512, 256), 256, 0, stream>>>(
            pbn, g1_bn_g, g1_bn_b, meanb, invb, out_xg1, G * 512, 512);
        gemm_bias_kernel<<<dim3(256 / 64, G / 64), 256, 0, stream>>>(
            out_xg1, f1_w1, f1_b1, hbuf, G, 256, 512, 1);
        gemm_bias_kernel<<<dim3(1, G / 64), 256, 0, stream>>>(
            hbuf, f1_w2, f1_b2, out_z1, G, 2, 256, 0);
    }
}

// Round 6
// 2635.329 us; speedup vs baseline: 1.3265x; 1.2472x over previous
//
#include <hip/hip_runtime.h>
#include <hip/hip_bf16.h>

// ---------------------------------------------------------------------------
// Problem constants
// ---------------------------------------------------------------------------
#define N0 100000
#define E0C 1600000
#define N1 100000
#define E1C 1600000
#define GCONST 512
#define F0C 93
#define F1C 43
#define OC0 (F0C * 10)   // 930
#define OC1 (F1C * 10)   // 430
#define BN_EPS 1e-5f

typedef __attribute__((ext_vector_type(8))) short short8;
typedef __attribute__((ext_vector_type(4))) float floatx4;

static __device__ __forceinline__ unsigned short f2bf(float f) {
    unsigned u = __float_as_uint(f);
    unsigned r = (u + 0x7FFF + ((u >> 16) & 1)) >> 16;   // RNE
    return (unsigned short)r;
}
static __device__ __forceinline__ float bf2f(unsigned short u) {
    return __uint_as_float(((unsigned)u) << 16);
}
static __device__ __forceinline__ float ldval(const float* p) { return *p; }
static __device__ __forceinline__ float ldval(const unsigned short* p) { return bf2f(*p); }

// ---------------------------------------------------------------------------
// zero ints
// ---------------------------------------------------------------------------
__global__ __launch_bounds__(256) void zero_int_kernel(int* __restrict__ p, int n) {
    int i = blockIdx.x * 256 + threadIdx.x;
    if (i < n) p[i] = 0;
}

// ---------------------------------------------------------------------------
// graph boundary search
// ---------------------------------------------------------------------------
__global__ __launch_bounds__(256) void find_starts_kernel(const int* __restrict__ batch,
                                                          int N, int G,
                                                          int* __restrict__ starts) {
    int g = blockIdx.x * 256 + threadIdx.x;
    if (g > G) return;
    if (g == G) { starts[G] = N; return; }
    int lo = 0, hi = N;
    while (lo < hi) {
        int mid = (lo + hi) >> 1;
        if (batch[mid] < g) lo = mid + 1; else hi = mid;
    }
    starts[g] = lo;
}

// ---------------------------------------------------------------------------
// CSR build
// ---------------------------------------------------------------------------
__global__ __launch_bounds__(256) void hist_kernel(const int* __restrict__ ei,
                                                   int E, int* __restrict__ deg) {
    int e = blockIdx.x * 256 + threadIdx.x;
    if (e >= E) return;
    atomicAdd(&deg[ei[E + e]], 1);
}

__global__ __launch_bounds__(1024) void scan_kernel(const int* __restrict__ deg,
                                                    int N, int E,
                                                    int* __restrict__ rowptr,
                                                    int* __restrict__ cursor) {
    __shared__ int part[1024];
    int tid = threadIdx.x;
    int chunk = (N + 1023) / 1024;
    int s = tid * chunk;
    int e = s + chunk < N ? s + chunk : N;
    int sum = 0;
    for (int i = s; i < e; ++i) sum += deg[i];
    part[tid] = sum;
    __syncthreads();
    for (int off = 1; off < 1024; off <<= 1) {
        int add = (tid >= off) ? part[tid - off] : 0;
        __syncthreads();
        part[tid] += add;
        __syncthreads();
    }
    int run = part[tid] - sum;
    for (int i = s; i < e; ++i) {
        rowptr[i] = run;
        cursor[i] = run;
        run += deg[i];
    }
    if (tid == 1023) rowptr[N] = E;
}

__global__ __launch_bounds__(256) void fill_kernel(const int* __restrict__ ei,
                                                   int E,
                                                   int* __restrict__ cursor,
                                                   int* __restrict__ col) {
    int e = blockIdx.x * 256 + threadIdx.x;
    if (e >= E) return;
    int src = ei[e];
    int dst = ei[E + e];
    int pos = atomicAdd(&cursor[dst], 1);
    col[pos] = src;
}

// ---------------------------------------------------------------------------
// weight transpose+convert: Wt[c][k] (bf16, [CPAD][KP], zero-padded) from
// W[k][c] fp32 [Fr][OCr]. grid=CPAD blocks, block=KP threads.
// ---------------------------------------------------------------------------
__global__ __launch_bounds__(128) void wt_prep_kernel(const float* __restrict__ W,
                                                      unsigned short* __restrict__ Wt,
                                                      int OCr, int Fr, int KP) {
    int c = blockIdx.x;
    int k = threadIdx.x;
    unsigned short v = 0;
    if (c < OCr && k < Fr) v = f2bf(W[(size_t)k * OCr + c]);
    Wt[(size_t)c * KP + k] = v;
}

// ---------------------------------------------------------------------------
// CSR gather-aggregate -> bf16 padded rows.
// blockDim = (FPAD, NPB). t[node][f] = bf16( x[node][f] + sum_j x[col[j]][f] )
// f in [F,KP) zero-filled (MFMA K-padding; d_ws is poisoned each call).
// ---------------------------------------------------------------------------
template<typename TIN, int F, int FPAD, int KP>
__global__ __launch_bounds__(256) void gather_bf16_kernel(unsigned short* __restrict__ t,
                                                          const TIN* __restrict__ x,
                                                          int SIN,
                                                          const int* __restrict__ rowptr,
                                                          const int* __restrict__ col,
                                                          int N) {
    int node = blockIdx.x * blockDim.y + threadIdx.y;
    int f = threadIdx.x;
    if (node >= N) return;
    if (f >= F) { t[(size_t)node * KP + f] = 0; return; }
    int s = rowptr[node], e = rowptr[node + 1];
    float a0 = ldval(x + (size_t)node * SIN + f);
    float a1 = 0.f, a2 = 0.f, a3 = 0.f;
    int j = s;
    for (; j + 3 < e; j += 4) {
        int s0 = col[j], s1 = col[j + 1], s2 = col[j + 2], s3 = col[j + 3];
        a0 += ldval(x + (size_t)s0 * SIN + f);
        a1 += ldval(x + (size_t)s1 * SIN + f);
        a2 += ldval(x + (size_t)s2 * SIN + f);
        a3 += ldval(x + (size_t)s3 * SIN + f);
    }
    for (; j < e; ++j) a0 += ldval(x + (size_t)col[j] * SIN + f);
    t[(size_t)node * KP + f] = f2bf((a0 + a1) + (a2 + a3));
}

// ---------------------------------------------------------------------------
// conv1 via MFMA 16x16x32 bf16: y = relu(t @ W + b), y stored bf16 [N][KP].
// wave handles 16 rows x NT*16 cols; Wt is [NT*16][KP] bf16 (B^T layout).
// ---------------------------------------------------------------------------
template<int KP, int KS, int NT>
__global__ __launch_bounds__(256) void conv1_mfma_kernel(const unsigned short* __restrict__ t,
                                                         const unsigned short* __restrict__ Wt,
                                                         const float* __restrict__ bias,
                                                         unsigned short* __restrict__ y,
                                                         int NC, int N) {
    int wave = threadIdx.x >> 6, lane = threadIdx.x & 63;
    int quad = lane >> 4, l15 = lane & 15;
    int r0 = (blockIdx.x * 4 + wave) * 16;
    const short8 z8 = {0, 0, 0, 0, 0, 0, 0, 0};
    short8 a[KS];
    int arow = r0 + l15;
#pragma unroll
    for (int ks = 0; ks < KS; ++ks)
        a[ks] = (arow < N) ? *(const short8*)(t + (size_t)arow * KP + ks * 32 + quad * 8) : z8;
#pragma unroll
    for (int nt = 0; nt < NT; ++nt) {
        int colb = nt * 16 + l15;
        floatx4 c = {0.f, 0.f, 0.f, 0.f};
#pragma unroll
        for (int ks = 0; ks < KS; ++ks) {
            short8 b = *(const short8*)(Wt + (size_t)colb * KP + ks * 32 + quad * 8);
            c = __builtin_amdgcn_mfma_f32_16x16x32_bf16(a[ks], b, c, 0, 0, 0);
        }
        float bc = (colb < NC) ? bias[colb] : 0.f;
#pragma unroll
        for (int r = 0; r < 4; ++r) {
            int row = r0 + quad * 4 + r;
            if (row < N) {
                float o = fmaxf(c[r] + bc, 0.f);
                y[(size_t)row * KP + colb] = f2bf(o);
            }
        }
    }
}

// ---------------------------------------------------------------------------
// conv2 + relu + mean/max pool via MFMA, fused per graph. No LDS.
// block = (256-col slab, graph); wave owns 64 cols (4 tiles), keeps 4*KS
// B-frags in registers, loops the graph's nodes in 16-row chunks:
// KS A-loads + 4*KS MFMA + masked relu/sum/max; cross-quad shfl reduce.
// Wt is [gridx*256][KP] bf16 zero-padded. pooled: [G][2*OC] (mean|max).
// ---------------------------------------------------------------------------
template<int KP, int KS>
__global__ __launch_bounds__(256) void conv2_pool_mfma_kernel(const unsigned short* __restrict__ t,
                                                              const unsigned short* __restrict__ Wt,
                                                              const float* __restrict__ bias,
                                                              const int* __restrict__ starts,
                                                              float* __restrict__ pooled,
                                                              int OC) {
    int wave = threadIdx.x >> 6, lane = threadIdx.x & 63;
    int quad = lane >> 4, l15 = lane & 15;
    int g = blockIdx.y;
    int cw0 = blockIdx.x * 256 + wave * 64;
    short8 bfr[4][KS];
    float bs[4];
#pragma unroll
    for (int ti = 0; ti < 4; ++ti) {
        int colb = cw0 + ti * 16 + l15;
#pragma unroll
        for (int ks = 0; ks < KS; ++ks)
            bfr[ti][ks] = *(const short8*)(Wt + (size_t)colb * KP + ks * 32 + quad * 8);
        bs[ti] = (colb < OC) ? bias[colb] : 0.f;
    }
    int s = starts[g], e = starts[g + 1];
    float sum[4] = {0.f, 0.f, 0.f, 0.f};
    float mx[4]  = {0.f, 0.f, 0.f, 0.f};   // relu outputs >= 0
    const short8 z8 = {0, 0, 0, 0, 0, 0, 0, 0};
    for (int ns = s; ns < e; ns += 16) {
        short8 a[KS];
        int arow = ns + l15;
        bool av = arow < e;
#pragma unroll
        for (int ks = 0; ks < KS; ++ks)
            a[ks] = av ? *(const short8*)(t + (size_t)arow * KP + ks * 32 + quad * 8) : z8;
        int rbase = ns + quad * 4;
#pragma unroll
        for (int ti = 0; ti < 4; ++ti) {
            floatx4 c = {0.f, 0.f, 0.f, 0.f};
#pragma unroll
            for (int ks = 0; ks < KS; ++ks)
                c = __builtin_amdgcn_mfma_f32_16x16x32_bf16(a[ks], bfr[ti][ks], c, 0, 0, 0);
#pragma unroll
            for (int r = 0; r < 4; ++r) {
                float o = fmaxf(c[r] + bs[ti], 0.f);
                if (rbase + r < e) {
                    sum[ti] += o;
                    mx[ti] = fmaxf(mx[ti], o);
                }
            }
        }
    }
    int cnt = e - s;
    float rc = 1.f / (float)(cnt > 0 ? cnt : 1);
#pragma unroll
    for (int ti = 0; ti < 4; ++ti) {
        float sv = sum[ti], mv = mx[ti];
        sv += __shfl_down(sv, 32);
        mv = fmaxf(mv, __shfl_down(mv, 32));
        sv += __shfl_down(sv, 16);
        mv = fmaxf(mv, __shfl_down(mv, 16));
        if (lane < 16) {
            int colb = cw0 + ti * 16 + l15;
            if (colb < OC) {
                size_t base = (size_t)g * (size_t)(2 * OC);
                pooled[base + colb] = sv * rc;
                pooled[base + OC + colb] = mv;
            }
        }
    }
}

// ---------------------------------------------------------------------------
// generic fp32 GEMM (MLP/heads): C = A@B + bias, optional relu. 64x64 tile.
// ---------------------------------------------------------------------------
__global__ __launch_bounds__(256) void gemm_bias_kernel(const float* __restrict__ A,
                                                        const float* __restrict__ B,
                                                        const float* __restrict__ bias,
                                                        float* __restrict__ C,
                                                        int M, int N, int K, int relu) {
    __shared__ float As[16][64];
    __shared__ float Bs[16][64];
    int tid = threadIdx.x;
    int tx = tid & 15, ty = tid >> 4;
    int m0 = blockIdx.y * 64, n0 = blockIdx.x * 64;
    float acc[4][4] = {};
    for (int k0 = 0; k0 < K; k0 += 16) {
#pragma unroll
        for (int i = 0; i < 4; ++i) {
            int lin = tid + i * 256;
            int m = lin >> 4, k = lin & 15;
            int gm = m0 + m, gk = k0 + k;
            As[k][m] = (gm < M && gk < K) ? A[(size_t)gm * K + gk] : 0.f;
        }
#pragma unroll
        for (int i = 0; i < 4; ++i) {
            int lin = tid + i * 256;
            int n = lin & 63, k = lin >> 6;
            int gn = n0 + n, gk = k0 + k;
            Bs[k][n] = (gk < K && gn < N) ? B[(size_t)gk * N + gn] : 0.f;
        }
        __syncthreads();
#pragma unroll
        for (int k = 0; k < 16; ++k) {
            float a[4], b[4];
#pragma unroll
            for (int i = 0; i < 4; ++i) a[i] = As[k][ty * 4 + i];
#pragma unroll
            for (int j = 0; j < 4; ++j) b[j] = Bs[k][tx * 4 + j];
#pragma unroll
            for (int i = 0; i < 4; ++i)
#pragma unroll
                for (int j = 0; j < 4; ++j)
                    acc[i][j] = fmaf(a[i], b[j], acc[i][j]);
        }
        __syncthreads();
    }
#pragma unroll
    for (int i = 0; i < 4; ++i) {
        int gm = m0 + ty * 4 + i;
        if (gm >= M) continue;
#pragma unroll
        for (int j = 0; j < 4; ++j) {
            int gn = n0 + tx * 4 + j;
            if (gn >= N) continue;
            float v = acc[i][j] + bias[gn];
            if (relu) v = fmaxf(v, 0.f);
            C[(size_t)gm * N + gn] = v;
        }
    }
}

// ---------------------------------------------------------------------------
// batchnorm stats + apply
// ---------------------------------------------------------------------------
__global__ __launch_bounds__(256) void bn_stats_kernel(const float* __restrict__ p,
                                                       int rows, int cols,
                                                       float* __restrict__ mean,
                                                       float* __restrict__ inv) {
    int c = blockIdx.x;
    float s = 0.f, s2 = 0.f;
    for (int r = threadIdx.x; r < rows; r += 256) {
        float v = p[(size_t)r * cols + c];
        s += v;
        s2 += v * v;
    }
    __shared__ float ls[256], ls2[256];
    ls[threadIdx.x] = s;
    ls2[threadIdx.x] = s2;
    __syncthreads();
    for (int st = 128; st > 0; st >>= 1) {
        if (threadIdx.x < st) {
            ls[threadIdx.x] += ls[threadIdx.x + st];
            ls2[threadIdx.x] += ls2[threadIdx.x + st];
        }
        __syncthreads();
    }
    if (threadIdx.x == 0) {
        float m = ls[0] / (float)rows;
        float var = ls2[0] / (float)rows - m * m;
        mean[c] = m;
        inv[c] = 1.f / sqrtf(var + BN_EPS);
    }
}

__global__ __launch_bounds__(256) void bn_apply_kernel(const float* __restrict__ p,
                                                       const float* __restrict__ gamma,
                                                       const float* __restrict__ beta,
                                                       const float* __restrict__ mean,
                                                       const float* __restrict__ inv,
                                                       float* __restrict__ outp,
                                                       int total, int cols) {
    int i = blockIdx.x * 256 + threadIdx.x;
    if (i >= total) return;
    int c = i & (cols - 1);
    outp[i] = gamma[c] * (p[i] - mean[c]) * inv[c] + beta[c];
}

// ---------------------------------------------------------------------------
// launch
// ---------------------------------------------------------------------------
static inline int ceildiv(int a, int b) { return (a + b - 1) / b; }

extern "C" void kernel_launch(void* const* d_in, const int* in_sizes, int n_in,
                              void* d_out, int out_size, void* d_ws, size_t ws_size,
                              hipStream_t stream) {
    const float* x0   = (const float*)d_in[0];
    const float* x1   = (const float*)d_in[1];
    const int*   ei0  = (const int*)d_in[2];
    const int*   ei1  = (const int*)d_in[3];
    const int*   bat0 = (const int*)d_in[4];
    const int*   bat1 = (const int*)d_in[5];
    const float* w_c1 = (const float*)d_in[6];
    const float* b_c1 = (const float*)d_in[7];
    const float* w_c2 = (const float*)d_in[8];
    const float* b_c2 = (const float*)d_in[9];
    const float* w_c3 = (const float*)d_in[10];
    const float* b_c3 = (const float*)d_in[11];
    const float* w_c4 = (const float*)d_in[12];
    const float* b_c4 = (const float*)d_in[13];
    const float* g0_w1 = (const float*)d_in[14];
    const float* g0_b1 = (const float*)d_in[15];
    const float* g0_w2 = (const float*)d_in[16];
    const float* g0_b2 = (const float*)d_in[17];
    const float* g0_bn_g = (const float*)d_in[18];
    const float* g0_bn_b = (const float*)d_in[19];
    const float* g1_w1 = (const float*)d_in[20];
    const float* g1_b1 = (const float*)d_in[21];
    const float* g1_w2 = (const float*)d_in[22];
    const float* g1_b2 = (const float*)d_in[23];
    const float* g1_bn_g = (const float*)d_in[24];
    const float* g1_bn_b = (const float*)d_in[25];
    const float* f0_w1 = (const float*)d_in[26];
    const float* f0_b1 = (const float*)d_in[27];
    const float* f0_w2 = (const float*)d_in[28];
    const float* f0_b2 = (const float*)d_in[29];
    const float* f1_w1 = (const float*)d_in[30];
    const float* f1_b1 = (const float*)d_in[31];
    const float* f1_w2 = (const float*)d_in[32];
    const float* f1_b2 = (const float*)d_in[33];

    float* out = (float*)d_out;
    float* out_z   = out;
    float* out_xg0 = out + 1024;
    float* out_xg1 = out + 1024 + 262144;
    float* out_z1  = out + 1024 + 262144 + 262144;

    // workspace carve (floats; all offsets multiples of 4 -> 16B aligned)
    float* ws = (float*)d_ws;
    size_t off = 0;
    auto alloc = [&](size_t n) { float* p = ws + off; off += n; return p; };
    unsigned short* t_bf = (unsigned short*)alloc((size_t)N0 * 96 / 2);  // bf16 [N][96]
    unsigned short* y_bf = (unsigned short*)alloc((size_t)N0 * 96 / 2);  // bf16 [N][96]
    unsigned short* wt_a = (unsigned short*)alloc(96 * 96 / 2);          // conv1 Wt (max 96x96)
    unsigned short* wt_b = (unsigned short*)alloc(1024 * 96 / 2);        // conv2 Wt (max 1024x96)
    // Union region C: CSR (graph phase) aliases MLP temps (dense phase).
    size_t csr_floats = (size_t)N0 + (N0 + 1) + N0 + E0C;
    size_t mlp_floats = (size_t)GCONST * 2 * OC0 + (size_t)GCONST * 2 * OC1 +
                        (size_t)GCONST * 1024 + (size_t)GCONST * 512 +
                        (size_t)GCONST * 256;
    float* regionC = alloc(csr_floats > mlp_floats ? csr_floats : mlp_floats);
    int* deg    = (int*)regionC;
    int* rowptr = deg + N0;
    int* cursor = rowptr + (N0 + 1);
    int* colb   = cursor + N0;
    float* pooled0 = regionC;
    float* pooled1 = pooled0 + (size_t)GCONST * 2 * OC0;
    float* m1      = pooled1 + (size_t)GCONST * 2 * OC1;
    float* pbn     = m1 + (size_t)GCONST * 1024;
    float* hbuf    = pbn + (size_t)GCONST * 512;
    float* meanb   = alloc(512);
    float* invb    = alloc(512);
    int*   starts0 = (int*)alloc(520);
    int*   starts1 = (int*)alloc(520);

    const int G = GCONST;

    // =========================== branch 0 (F=93, KP=96) ===========================
    {
        const int N = N0, E = E0C, OC = OC0;
        find_starts_kernel<<<3, 256, 0, stream>>>(bat0, N, G, starts0);
        zero_int_kernel<<<ceildiv(N, 256), 256, 0, stream>>>(deg, N);
        hist_kernel<<<ceildiv(E, 256), 256, 0, stream>>>(ei0, E, deg);
        scan_kernel<<<1, 1024, 0, stream>>>(deg, N, E, rowptr, cursor);
        fill_kernel<<<ceildiv(E, 256), 256, 0, stream>>>(ei0, E, cursor, colb);
        // weight prep (bf16, transposed, zero-padded)
        wt_prep_kernel<<<96, 96, 0, stream>>>(w_c1, wt_a, 93, 93, 96);
        wt_prep_kernel<<<1024, 96, 0, stream>>>(w_c2, wt_b, 930, 93, 96);
        // conv1: t = x + agg(x) [bf16]; y = relu(t @ w1 + b1) [bf16]
        gather_bf16_kernel<float, 93, 96, 96><<<ceildiv(N, 2), dim3(96, 2), 0, stream>>>(
            t_bf, x0, 93, rowptr, colb, N);
        conv1_mfma_kernel<96, 3, 6><<<ceildiv(N, 64), 256, 0, stream>>>(
            t_bf, wt_a, b_c1, y_bf, 93, N);
        // conv2 aggregate + fused GEMM-pool
        gather_bf16_kernel<unsigned short, 93, 96, 96><<<ceildiv(N, 2), dim3(96, 2), 0, stream>>>(
            t_bf, y_bf, 96, rowptr, colb, N);
        conv2_pool_mfma_kernel<96, 3><<<dim3(4, G), 256, 0, stream>>>(
            t_bf, wt_b, b_c2, starts0, pooled0, OC);
        // MLP (fp32)
        gemm_bias_kernel<<<dim3(1024 / 64, G / 64), 256, 0, stream>>>(
            pooled0, g0_w1, g0_b1, m1, G, 1024, 2 * OC, 1);
        gemm_bias_kernel<<<dim3(512 / 64, G / 64), 256, 0, stream>>>(
            m1, g0_w2, g0_b2, pbn, G, 512, 1024, 0);
        bn_stats_kernel<<<512, 256, 0, stream>>>(pbn, G, 512, meanb, invb);
        bn_apply_kernel<<<ceildiv(G * 512, 256), 256, 0, stream>>>(
            pbn, g0_bn_g, g0_bn_b, meanb, invb, out_xg0, G * 512, 512);
        gemm_bias_kernel<<<dim3(256 / 64, G / 64), 256, 0, stream>>>(
            out_xg0, f0_w1, f0_b1, hbuf, G, 256, 512, 1);
        gemm_bias_kernel<<<dim3(1, G / 64), 256, 0, stream>>>(
            hbuf, f0_w2, f0_b2, out_z, G, 2, 256, 0);
    }

    // =========================== branch 1 (F=43, KP=64) ===========================
    {
        const int N = N1, E = E1C, OC = OC1;
        find_starts_kernel<<<3, 256, 0, stream>>>(bat1, N, G, starts1);
        zero_int_kernel<<<ceildiv(N, 256), 256, 0, stream>>>(deg, N);
        hist_kernel<<<ceildiv(E, 256), 256, 0, stream>>>(ei1, E, deg);
        scan_kernel<<<1, 1024, 0, stream>>>(deg, N, E, rowptr, cursor);
        fill_kernel<<<ceildiv(E, 256), 256, 0, stream>>>(ei1, E, cursor, colb);
        wt_prep_kernel<<<48, 64, 0, stream>>>(w_c3, wt_a, 43, 43, 64);
        wt_prep_kernel<<<512, 64, 0, stream>>>(w_c4, wt_b, 430, 43, 64);
        gather_bf16_kernel<float, 43, 64, 64><<<ceildiv(N, 4), dim3(64, 4), 0, stream>>>(
            t_bf, x1, 43, rowptr, colb, N);
        conv1_mfma_kernel<64, 2, 3><<<ceildiv(N, 64), 256, 0, stream>>>(
            t_bf, wt_a, b_c3, y_bf, 43, N);
        gather_bf16_kernel<unsigned short, 43, 64, 64><<<ceildiv(N, 4), dim3(64, 4), 0, stream>>>(
            t_bf, y_bf, 64, rowptr, colb, N);
        conv2_pool_mfma_kernel<64, 2><<<dim3(2, G), 256, 0, stream>>>(
            t_bf, wt_b, b_c4, starts1, pooled1, OC);
        gemm_bias_kernel<<<dim3(1024 / 64, G / 64), 256, 0, stream>>>(
            pooled1, g1_w1, g1_b1, m1, G, 1024, 2 * OC, 1);
        gemm_bias_kernel<<<dim3(512 / 64, G / 64), 256, 0, stream>>>(
            m1, g1_w2, g1_b2, pbn, G, 512, 1024, 0);
        bn_stats_kernel<<<512, 256, 0, stream>>>(pbn, G, 512, meanb, invb);
        bn_apply_kernel<<<ceildiv(G * 512, 256), 256, 0, stream>>>(
            pbn, g1_bn_g, g1_bn_b, meanb, invb, out_xg1, G * 512, 512);
        gemm_bias_kernel<<<dim3(256 / 64, G / 64), 256, 0, stream>>>(
            out_xg1, f1_w1, f1_b1, hbuf, G, 256, 512, 1);
        gemm_bias_kernel<<<dim3(1, G / 64), 256, 0, stream>>>(
            hbuf, f1_w2, f1_b2, out_z1, G, 2, 256, 0);
    }
}

// Round 7
// 1665.810 us; speedup vs baseline: 2.0986x; 1.5820x over previous
//
#include <hip/hip_runtime.h>
#include <hip/hip_bf16.h>

// ---------------------------------------------------------------------------
// Problem constants
// ---------------------------------------------------------------------------
#define N0 100000
#define E0C 1600000
#define N1 100000
#define E1C 1600000
#define GCONST 512
#define F0C 93
#define F1C 43
#define OC0 (F0C * 10)   // 930
#define OC1 (F1C * 10)   // 430
#define BN_EPS 1e-5f

typedef __attribute__((ext_vector_type(8))) short short8;
typedef __attribute__((ext_vector_type(4))) float floatx4;

static __device__ __forceinline__ unsigned short f2bf(float f) {
    unsigned u = __float_as_uint(f);
    unsigned r = (u + 0x7FFF + ((u >> 16) & 1)) >> 16;   // RNE
    return (unsigned short)r;
}
static __device__ __forceinline__ float bf2f(unsigned short u) {
    return __uint_as_float(((unsigned)u) << 16);
}
static __device__ __forceinline__ float ldval(const float* p) { return *p; }
static __device__ __forceinline__ float ldval(const unsigned short* p) { return bf2f(*p); }

// ---------------------------------------------------------------------------
// zero ints
// ---------------------------------------------------------------------------
__global__ __launch_bounds__(256) void zero_int_kernel(int* __restrict__ p, int n) {
    int i = blockIdx.x * 256 + threadIdx.x;
    if (i < n) p[i] = 0;
}

// ---------------------------------------------------------------------------
// graph boundary search
// ---------------------------------------------------------------------------
__global__ __launch_bounds__(256) void find_starts_kernel(const int* __restrict__ batch,
                                                          int N, int G,
                                                          int* __restrict__ starts) {
    int g = blockIdx.x * 256 + threadIdx.x;
    if (g > G) return;
    if (g == G) { starts[G] = N; return; }
    int lo = 0, hi = N;
    while (lo < hi) {
        int mid = (lo + hi) >> 1;
        if (batch[mid] < g) lo = mid + 1; else hi = mid;
    }
    starts[g] = lo;
}

// ---------------------------------------------------------------------------
// CSR build
// ---------------------------------------------------------------------------
__global__ __launch_bounds__(256) void hist_kernel(const int* __restrict__ ei,
                                                   int E, int* __restrict__ deg) {
    int e = blockIdx.x * 256 + threadIdx.x;
    if (e >= E) return;
    atomicAdd(&deg[ei[E + e]], 1);
}

__global__ __launch_bounds__(1024) void scan_kernel(const int* __restrict__ deg,
                                                    int N, int E,
                                                    int* __restrict__ rowptr,
                                                    int* __restrict__ cursor) {
    __shared__ int part[1024];
    int tid = threadIdx.x;
    int chunk = (N + 1023) / 1024;
    int s = tid * chunk;
    int e = s + chunk < N ? s + chunk : N;
    int sum = 0;
    for (int i = s; i < e; ++i) sum += deg[i];
    part[tid] = sum;
    __syncthreads();
    for (int off = 1; off < 1024; off <<= 1) {
        int add = (tid >= off) ? part[tid - off] : 0;
        __syncthreads();
        part[tid] += add;
        __syncthreads();
    }
    int run = part[tid] - sum;
    for (int i = s; i < e; ++i) {
        rowptr[i] = run;
        cursor[i] = run;
        run += deg[i];
    }
    if (tid == 1023) rowptr[N] = E;
}

__global__ __launch_bounds__(256) void fill_kernel(const int* __restrict__ ei,
                                                   int E,
                                                   int* __restrict__ cursor,
                                                   int* __restrict__ col) {
    int e = blockIdx.x * 256 + threadIdx.x;
    if (e >= E) return;
    int src = ei[e];
    int dst = ei[E + e];
    int pos = atomicAdd(&cursor[dst], 1);
    col[pos] = src;
}

// ---------------------------------------------------------------------------
// weight transpose+convert: Wt[c][k] (bf16, [CPAD][KP], zero-padded)
// ---------------------------------------------------------------------------
__global__ __launch_bounds__(128) void wt_prep_kernel(const float* __restrict__ W,
                                                      unsigned short* __restrict__ Wt,
                                                      int OCr, int Fr, int KP) {
    int c = blockIdx.x;
    int k = threadIdx.x;
    unsigned short v = 0;
    if (c < OCr && k < Fr) v = f2bf(W[(size_t)k * OCr + c]);
    Wt[(size_t)c * KP + k] = v;
}

// ---------------------------------------------------------------------------
// CSR gather-aggregate -> bf16 padded rows
// ---------------------------------------------------------------------------
template<typename TIN, int F, int FPAD, int KP>
__global__ __launch_bounds__(256) void gather_bf16_kernel(unsigned short* __restrict__ t,
                                                          const TIN* __restrict__ x,
                                                          int SIN,
                                                          const int* __restrict__ rowptr,
                                                          const int* __restrict__ col,
                                                          int N) {
    int node = blockIdx.x * blockDim.y + threadIdx.y;
    int f = threadIdx.x;
    if (node >= N) return;
    if (f >= F) { t[(size_t)node * KP + f] = 0; return; }
    int s = rowptr[node], e = rowptr[node + 1];
    float a0 = ldval(x + (size_t)node * SIN + f);
    float a1 = 0.f, a2 = 0.f, a3 = 0.f;
    int j = s;
    for (; j + 3 < e; j += 4) {
        int s0 = col[j], s1 = col[j + 1], s2 = col[j + 2], s3 = col[j + 3];
        a0 += ldval(x + (size_t)s0 * SIN + f);
        a1 += ldval(x + (size_t)s1 * SIN + f);
        a2 += ldval(x + (size_t)s2 * SIN + f);
        a3 += ldval(x + (size_t)s3 * SIN + f);
    }
    for (; j < e; ++j) a0 += ldval(x + (size_t)col[j] * SIN + f);
    t[(size_t)node * KP + f] = f2bf((a0 + a1) + (a2 + a3));
}

// ---------------------------------------------------------------------------
// conv1 via MFMA 16x16x32 bf16: y = relu(t @ W + b), y stored bf16 [N][KP]
// ---------------------------------------------------------------------------
template<int KP, int KS, int NT>
__global__ __launch_bounds__(256) void conv1_mfma_kernel(const unsigned short* __restrict__ t,
                                                         const unsigned short* __restrict__ Wt,
                                                         const float* __restrict__ bias,
                                                         unsigned short* __restrict__ y,
                                                         int NC, int N) {
    int wave = threadIdx.x >> 6, lane = threadIdx.x & 63;
    int quad = lane >> 4, l15 = lane & 15;
    int r0 = (blockIdx.x * 4 + wave) * 16;
    const short8 z8 = {0, 0, 0, 0, 0, 0, 0, 0};
    short8 a[KS];
    int arow = r0 + l15;
#pragma unroll
    for (int ks = 0; ks < KS; ++ks)
        a[ks] = (arow < N) ? *(const short8*)(t + (size_t)arow * KP + ks * 32 + quad * 8) : z8;
#pragma unroll
    for (int nt = 0; nt < NT; ++nt) {
        int colb = nt * 16 + l15;
        floatx4 c = {0.f, 0.f, 0.f, 0.f};
#pragma unroll
        for (int ks = 0; ks < KS; ++ks) {
            short8 b = *(const short8*)(Wt + (size_t)colb * KP + ks * 32 + quad * 8);
            c = __builtin_amdgcn_mfma_f32_16x16x32_bf16(a[ks], b, c, 0, 0, 0);
        }
        float bc = (colb < NC) ? bias[colb] : 0.f;
#pragma unroll
        for (int r = 0; r < 4; ++r) {
            int row = r0 + quad * 4 + r;
            if (row < N) {
                float o = fmaxf(c[r] + bc, 0.f);
                y[(size_t)row * KP + colb] = f2bf(o);
            }
        }
    }
}

// ---------------------------------------------------------------------------
// conv2 + relu + mean/max pool via MFMA, fused per graph. No LDS.
// ---------------------------------------------------------------------------
template<int KP, int KS>
__global__ __launch_bounds__(256) void conv2_pool_mfma_kernel(const unsigned short* __restrict__ t,
                                                              const unsigned short* __restrict__ Wt,
                                                              const float* __restrict__ bias,
                                                              const int* __restrict__ starts,
                                                              float* __restrict__ pooled,
                                                              int OC) {
    int wave = threadIdx.x >> 6, lane = threadIdx.x & 63;
    int quad = lane >> 4, l15 = lane & 15;
    int g = blockIdx.y;
    int cw0 = blockIdx.x * 256 + wave * 64;
    short8 bfr[4][KS];
    float bs[4];
#pragma unroll
    for (int ti = 0; ti < 4; ++ti) {
        int colb = cw0 + ti * 16 + l15;
#pragma unroll
        for (int ks = 0; ks < KS; ++ks)
            bfr[ti][ks] = *(const short8*)(Wt + (size_t)colb * KP + ks * 32 + quad * 8);
        bs[ti] = (colb < OC) ? bias[colb] : 0.f;
    }
    int s = starts[g], e = starts[g + 1];
    float sum[4] = {0.f, 0.f, 0.f, 0.f};
    float mx[4]  = {0.f, 0.f, 0.f, 0.f};
    const short8 z8 = {0, 0, 0, 0, 0, 0, 0, 0};
    for (int ns = s; ns < e; ns += 16) {
        short8 a[KS];
        int arow = ns + l15;
        bool av = arow < e;
#pragma unroll
        for (int ks = 0; ks < KS; ++ks)
            a[ks] = av ? *(const short8*)(t + (size_t)arow * KP + ks * 32 + quad * 8) : z8;
        int rbase = ns + quad * 4;
#pragma unroll
        for (int ti = 0; ti < 4; ++ti) {
            floatx4 c = {0.f, 0.f, 0.f, 0.f};
#pragma unroll
            for (int ks = 0; ks < KS; ++ks)
                c = __builtin_amdgcn_mfma_f32_16x16x32_bf16(a[ks], bfr[ti][ks], c, 0, 0, 0);
#pragma unroll
            for (int r = 0; r < 4; ++r) {
                float o = fmaxf(c[r] + bs[ti], 0.f);
                if (rbase + r < e) {
                    sum[ti] += o;
                    mx[ti] = fmaxf(mx[ti], o);
                }
            }
        }
    }
    int cnt = e - s;
    float rc = 1.f / (float)(cnt > 0 ? cnt : 1);
#pragma unroll
    for (int ti = 0; ti < 4; ++ti) {
        float sv = sum[ti], mv = mx[ti];
        sv += __shfl_down(sv, 32);
        mv = fmaxf(mv, __shfl_down(mv, 32));
        sv += __shfl_down(sv, 16);
        mv = fmaxf(mv, __shfl_down(mv, 16));
        if (lane < 16) {
            int colb = cw0 + ti * 16 + l15;
            if (colb < OC) {
                size_t base = (size_t)g * (size_t)(2 * OC);
                pooled[base + colb] = sv * rc;
                pooled[base + OC + colb] = mv;
            }
        }
    }
}

// ---------------------------------------------------------------------------
// split-K fp32 GEMM: Cpart[z] = A[M x K-slice] @ B[K-slice x N].
// Partials per z-slice (no atomics). As padded to stride 68 (2-way max
// conflict on staging, free). Grid (N/64, M/64, S); KC = K-chunk (mult of 16).
// Previous single-slice GEMM: 128 blocks -> Occupancy 5.9%, VALUBusy 4%,
// pure latency-bound at 406 us. Split-K restores block-level parallelism.
// ---------------------------------------------------------------------------
__global__ __launch_bounds__(256) void gemm_splitk_kernel(const float* __restrict__ A,
                                                          const float* __restrict__ B,
                                                          float* __restrict__ Cpart,
                                                          int M, int N, int K, int KC) {
    __shared__ float As[16][68];
    __shared__ float Bs[16][64];
    int tid = threadIdx.x;
    int tx = tid & 15, ty = tid >> 4;
    int m0 = blockIdx.y * 64, n0 = blockIdx.x * 64;
    int ks = blockIdx.z * KC;
    int ke = ks + KC < K ? ks + KC : K;
    float acc[4][4] = {};
    for (int k0 = ks; k0 < ke; k0 += 16) {
#pragma unroll
        for (int i = 0; i < 4; ++i) {
            int lin = tid + i * 256;
            int m = lin >> 4, k = lin & 15;
            int gm = m0 + m, gk = k0 + k;
            As[k][m] = (gm < M && gk < ke) ? A[(size_t)gm * K + gk] : 0.f;
        }
#pragma unroll
        for (int i = 0; i < 4; ++i) {
            int lin = tid + i * 256;
            int n = lin & 63, k = lin >> 6;
            int gn = n0 + n, gk = k0 + k;
            Bs[k][n] = (gk < ke && gn < N) ? B[(size_t)gk * N + gn] : 0.f;
        }
        __syncthreads();
#pragma unroll
        for (int k = 0; k < 16; ++k) {
            float a[4], b[4];
#pragma unroll
            for (int i = 0; i < 4; ++i) a[i] = As[k][ty * 4 + i];
#pragma unroll
            for (int j = 0; j < 4; ++j) b[j] = Bs[k][tx * 4 + j];
#pragma unroll
            for (int i = 0; i < 4; ++i)
#pragma unroll
                for (int j = 0; j < 4; ++j)
                    acc[i][j] = fmaf(a[i], b[j], acc[i][j]);
        }
        __syncthreads();
    }
    size_t base = (size_t)blockIdx.z * M * N;
#pragma unroll
    for (int i = 0; i < 4; ++i) {
        int gm = m0 + ty * 4 + i;
        if (gm >= M) continue;
#pragma unroll
        for (int j = 0; j < 4; ++j) {
            int gn = n0 + tx * 4 + j;
            if (gn >= N) continue;
            Cpart[base + (size_t)gm * N + gn] = acc[i][j];
        }
    }
}

// reduce S partials + bias (+relu). Nmask = N-1 (N pow2).
__global__ __launch_bounds__(256) void reduce_bias_kernel(const float* __restrict__ Cpart,
                                                          const float* __restrict__ bias,
                                                          float* __restrict__ C,
                                                          int MN, int Nmask, int S, int relu) {
    int i = blockIdx.x * 256 + threadIdx.x;
    if (i >= MN) return;
    float s = 0.f;
    for (int z = 0; z < S; ++z) s += Cpart[(size_t)z * MN + i];
    s += bias[i & Nmask];
    if (relu) s = fmaxf(s, 0.f);
    C[i] = s;
}

// ---------------------------------------------------------------------------
// head2: z[row][0..1] = h[row][0..255] @ w2[256][2] + b2. Wave per row.
// ---------------------------------------------------------------------------
__global__ __launch_bounds__(256) void head2_kernel(const float* __restrict__ h,
                                                    const float* __restrict__ w2,
                                                    const float* __restrict__ b2,
                                                    float* __restrict__ z, int M) {
    int wave = threadIdx.x >> 6, lane = threadIdx.x & 63;
    int row = blockIdx.x * 4 + wave;
    if (row >= M) return;
    float4 hv = *(const float4*)(h + (size_t)row * 256 + lane * 4);
    const float* wp = w2 + lane * 8;   // w2[k][c], k = lane*4.., c in {0,1}
    float s0 = hv.x * wp[0] + hv.y * wp[2] + hv.z * wp[4] + hv.w * wp[6];
    float s1 = hv.x * wp[1] + hv.y * wp[3] + hv.z * wp[5] + hv.w * wp[7];
#pragma unroll
    for (int off = 32; off >= 1; off >>= 1) {
        s0 += __shfl_down(s0, off);
        s1 += __shfl_down(s1, off);
    }
    if (lane == 0) {
        z[(size_t)row * 2 + 0] = s0 + b2[0];
        z[(size_t)row * 2 + 1] = s1 + b2[1];
    }
}

// ---------------------------------------------------------------------------
// batchnorm stats + apply
// ---------------------------------------------------------------------------
__global__ __launch_bounds__(256) void bn_stats_kernel(const float* __restrict__ p,
                                                       int rows, int cols,
                                                       float* __restrict__ mean,
                                                       float* __restrict__ inv) {
    int c = blockIdx.x;
    float s = 0.f, s2 = 0.f;
    for (int r = threadIdx.x; r < rows; r += 256) {
        float v = p[(size_t)r * cols + c];
        s += v;
        s2 += v * v;
    }
    __shared__ float ls[256], ls2[256];
    ls[threadIdx.x] = s;
    ls2[threadIdx.x] = s2;
    __syncthreads();
    for (int st = 128; st > 0; st >>= 1) {
        if (threadIdx.x < st) {
            ls[threadIdx.x] += ls[threadIdx.x + st];
            ls2[threadIdx.x] += ls2[threadIdx.x + st];
        }
        __syncthreads();
    }
    if (threadIdx.x == 0) {
        float m = ls[0] / (float)rows;
        float var = ls2[0] / (float)rows - m * m;
        mean[c] = m;
        inv[c] = 1.f / sqrtf(var + BN_EPS);
    }
}

__global__ __launch_bounds__(256) void bn_apply_kernel(const float* __restrict__ p,
                                                       const float* __restrict__ gamma,
                                                       const float* __restrict__ beta,
                                                       const float* __restrict__ mean,
                                                       const float* __restrict__ inv,
                                                       float* __restrict__ outp,
                                                       int total, int cols) {
    int i = blockIdx.x * 256 + threadIdx.x;
    if (i >= total) return;
    int c = i & (cols - 1);
    outp[i] = gamma[c] * (p[i] - mean[c]) * inv[c] + beta[c];
}

// ---------------------------------------------------------------------------
// launch
// ---------------------------------------------------------------------------
static inline int ceildiv(int a, int b) { return (a + b - 1) / b; }

extern "C" void kernel_launch(void* const* d_in, const int* in_sizes, int n_in,
                              void* d_out, int out_size, void* d_ws, size_t ws_size,
                              hipStream_t stream) {
    const float* x0   = (const float*)d_in[0];
    const float* x1   = (const float*)d_in[1];
    const int*   ei0  = (const int*)d_in[2];
    const int*   ei1  = (const int*)d_in[3];
    const int*   bat0 = (const int*)d_in[4];
    const int*   bat1 = (const int*)d_in[5];
    const float* w_c1 = (const float*)d_in[6];
    const float* b_c1 = (const float*)d_in[7];
    const float* w_c2 = (const float*)d_in[8];
    const float* b_c2 = (const float*)d_in[9];
    const float* w_c3 = (const float*)d_in[10];
    const float* b_c3 = (const float*)d_in[11];
    const float* w_c4 = (const float*)d_in[12];
    const float* b_c4 = (const float*)d_in[13];
    const float* g0_w1 = (const float*)d_in[14];
    const float* g0_b1 = (const float*)d_in[15];
    const float* g0_w2 = (const float*)d_in[16];
    const float* g0_b2 = (const float*)d_in[17];
    const float* g0_bn_g = (const float*)d_in[18];
    const float* g0_bn_b = (const float*)d_in[19];
    const float* g1_w1 = (const float*)d_in[20];
    const float* g1_b1 = (const float*)d_in[21];
    const float* g1_w2 = (const float*)d_in[22];
    const float* g1_b2 = (const float*)d_in[23];
    const float* g1_bn_g = (const float*)d_in[24];
    const float* g1_bn_b = (const float*)d_in[25];
    const float* f0_w1 = (const float*)d_in[26];
    const float* f0_b1 = (const float*)d_in[27];
    const float* f0_w2 = (const float*)d_in[28];
    const float* f0_b2 = (const float*)d_in[29];
    const float* f1_w1 = (const float*)d_in[30];
    const float* f1_b1 = (const float*)d_in[31];
    const float* f1_w2 = (const float*)d_in[32];
    const float* f1_b2 = (const float*)d_in[33];

    float* out = (float*)d_out;
    float* out_z   = out;
    float* out_xg0 = out + 1024;
    float* out_xg1 = out + 1024 + 262144;
    float* out_z1  = out + 1024 + 262144 + 262144;

    // workspace carve (floats; all offsets multiples of 4 -> 16B aligned)
    float* ws = (float*)d_ws;
    size_t off = 0;
    auto alloc = [&](size_t n) { float* p = ws + off; off += n; return p; };
    unsigned short* t_bf = (unsigned short*)alloc((size_t)N0 * 96 / 2);  // bf16 [N][96]
    unsigned short* y_bf = (unsigned short*)alloc((size_t)N0 * 96 / 2);  // bf16 [N][96]
    unsigned short* wt_a = (unsigned short*)alloc(96 * 96 / 2);          // conv1 Wt
    unsigned short* wt_b = (unsigned short*)alloc(1024 * 96 / 2);        // conv2 Wt
    float* cpart = alloc((size_t)8 * 512 * 1024);                        // split-K partials
    // Union region C: CSR (graph phase) aliases MLP temps (dense phase).
    size_t csr_floats = (size_t)N0 + (N0 + 1) + N0 + E0C;
    size_t mlp_floats = (size_t)GCONST * 2 * OC0 + (size_t)GCONST * 2 * OC1 +
                        (size_t)GCONST * 1024 + (size_t)GCONST * 512 +
                        (size_t)GCONST * 256;
    float* regionC = alloc(csr_floats > mlp_floats ? csr_floats : mlp_floats);
    int* deg    = (int*)regionC;
    int* rowptr = deg + N0;
    int* cursor = rowptr + (N0 + 1);
    int* colb   = cursor + N0;
    float* pooled0 = regionC;
    float* pooled1 = pooled0 + (size_t)GCONST * 2 * OC0;
    float* m1      = pooled1 + (size_t)GCONST * 2 * OC1;
    float* pbn     = m1 + (size_t)GCONST * 1024;
    float* hbuf    = pbn + (size_t)GCONST * 512;
    float* meanb   = alloc(512);
    float* invb    = alloc(512);
    int*   starts0 = (int*)alloc(520);
    int*   starts1 = (int*)alloc(520);

    const int G = GCONST;

    // =========================== branch 0 (F=93, KP=96) ===========================
    {
        const int N = N0, E = E0C, OC = OC0;
        find_starts_kernel<<<3, 256, 0, stream>>>(bat0, N, G, starts0);
        zero_int_kernel<<<ceildiv(N, 256), 256, 0, stream>>>(deg, N);
        hist_kernel<<<ceildiv(E, 256), 256, 0, stream>>>(ei0, E, deg);
        scan_kernel<<<1, 1024, 0, stream>>>(deg, N, E, rowptr, cursor);
        fill_kernel<<<ceildiv(E, 256), 256, 0, stream>>>(ei0, E, cursor, colb);
        wt_prep_kernel<<<96, 96, 0, stream>>>(w_c1, wt_a, 93, 93, 96);
        wt_prep_kernel<<<1024, 96, 0, stream>>>(w_c2, wt_b, 930, 93, 96);
        gather_bf16_kernel<float, 93, 96, 96><<<ceildiv(N, 2), dim3(96, 2), 0, stream>>>(
            t_bf, x0, 93, rowptr, colb, N);
        conv1_mfma_kernel<96, 3, 6><<<ceildiv(N, 64), 256, 0, stream>>>(
            t_bf, wt_a, b_c1, y_bf, 93, N);
        gather_bf16_kernel<unsigned short, 93, 96, 96><<<ceildiv(N, 2), dim3(96, 2), 0, stream>>>(
            t_bf, y_bf, 96, rowptr, colb, N);
        conv2_pool_mfma_kernel<96, 3><<<dim3(4, G), 256, 0, stream>>>(
            t_bf, wt_b, b_c2, starts0, pooled0, OC);
        // MLP (fp32, split-K)
        gemm_splitk_kernel<<<dim3(16, 8, 8), 256, 0, stream>>>(
            pooled0, g0_w1, cpart, G, 1024, 2 * OC, 240);
        reduce_bias_kernel<<<ceildiv(G * 1024, 256), 256, 0, stream>>>(
            cpart, g0_b1, m1, G * 1024, 1023, 8, 1);
        gemm_splitk_kernel<<<dim3(8, 8, 8), 256, 0, stream>>>(
            m1, g0_w2, cpart, G, 512, 1024, 128);
        reduce_bias_kernel<<<ceildiv(G * 512, 256), 256, 0, stream>>>(
            cpart, g0_b2, pbn, G * 512, 511, 8, 0);
        bn_stats_kernel<<<512, 256, 0, stream>>>(pbn, G, 512, meanb, invb);
        bn_apply_kernel<<<ceildiv(G * 512, 256), 256, 0, stream>>>(
            pbn, g0_bn_g, g0_bn_b, meanb, invb, out_xg0, G * 512, 512);
        // head
        gemm_splitk_kernel<<<dim3(4, 8, 8), 256, 0, stream>>>(
            out_xg0, f0_w1, cpart, G, 256, 512, 64);
        reduce_bias_kernel<<<ceildiv(G * 256, 256), 256, 0, stream>>>(
            cpart, f0_b1, hbuf, G * 256, 255, 8, 1);
        head2_kernel<<<G / 4, 256, 0, stream>>>(hbuf, f0_w2, f0_b2, out_z, G);
    }

    // =========================== branch 1 (F=43, KP=64) ===========================
    {
        const int N = N1, E = E1C, OC = OC1;
        find_starts_kernel<<<3, 256, 0, stream>>>(bat1, N, G, starts1);
        zero_int_kernel<<<ceildiv(N, 256), 256, 0, stream>>>(deg, N);
        hist_kernel<<<ceildiv(E, 256), 256, 0, stream>>>(ei1, E, deg);
        scan_kernel<<<1, 1024, 0, stream>>>(deg, N, E, rowptr, cursor);
        fill_kernel<<<ceildiv(E, 256), 256, 0, stream>>>(ei1, E, cursor, colb);
        wt_prep_kernel<<<48, 64, 0, stream>>>(w_c3, wt_a, 43, 43, 64);
        wt_prep_kernel<<<512, 64, 0, stream>>>(w_c4, wt_b, 430, 43, 64);
        gather_bf16_kernel<float, 43, 64, 64><<<ceildiv(N, 4), dim3(64, 4), 0, stream>>>(
            t_bf, x1, 43, rowptr, colb, N);
        conv1_mfma_kernel<64, 2, 3><<<ceildiv(N, 64), 256, 0, stream>>>(
            t_bf, wt_a, b_c3, y_bf, 43, N);
        gather_bf16_kernel<unsigned short, 43, 64, 64><<<ceildiv(N, 4), dim3(64, 4), 0, stream>>>(
            t_bf, y_bf, 64, rowptr, colb, N);
        conv2_pool_mfma_kernel<64, 2><<<dim3(2, G), 256, 0, stream>>>(
            t_bf, wt_b, b_c4, starts1, pooled1, OC);
        gemm_splitk_kernel<<<dim3(16, 8, 8), 256, 0, stream>>>(
            pooled1, g1_w1, cpart, G, 1024, 2 * OC, 112);
        reduce_bias_kernel<<<ceildiv(G * 1024, 256), 256, 0, stream>>>(
            cpart, g1_b1, m1, G * 1024, 1023, 8, 1);
        gemm_splitk_kernel<<<dim3(8, 8, 8), 256, 0, stream>>>(
            m1, g1_w2, cpart, G, 512, 1024, 128);
        reduce_bias_kernel<<<ceildiv(G * 512, 256), 256, 0, stream>>>(
            cpart, g1_b2, pbn, G * 512, 511, 8, 0);
        bn_stats_kernel<<<512, 256, 0, stream>>>(pbn, G, 512, meanb, invb);
        bn_apply_kernel<<<ceildiv(G * 512, 256), 256, 0, stream>>>(
            pbn, g1_bn_g, g1_bn_b, meanb, invb, out_xg1, G * 512, 512);
        gemm_splitk_kernel<<<dim3(4, 8, 8), 256, 0, stream>>>(
            out_xg1, f1_w1, cpart, G, 256, 512, 64);
        reduce_bias_kernel<<<ceildiv(G * 256, 256), 256, 0, stream>>>(
            cpart, f1_b1, hbuf, G * 256, 255, 8, 1);
        head2_kernel<<<G / 4, 256, 0, stream>>>(hbuf, f1_w2, f1_b2, out_z1, G);
    }
}

// Round 8
// 1235.686 us; speedup vs baseline: 2.8290x; 1.3481x over previous
//
#include <hip/hip_runtime.h>
#include <hip/hip_bf16.h>

// ---------------------------------------------------------------------------
// Problem constants
// ---------------------------------------------------------------------------
#define N0 100000
#define E0C 1600000
#define N1 100000
#define E1C 1600000
#define GCONST 512
#define F0C 93
#define F1C 43
#define OC0 (F0C * 10)   // 930
#define OC1 (F1C * 10)   // 430
#define BN_EPS 1e-5f

typedef __attribute__((ext_vector_type(8))) short short8;
typedef __attribute__((ext_vector_type(4))) float floatx4;

static __device__ __forceinline__ unsigned short f2bf(float f) {
    unsigned u = __float_as_uint(f);
    unsigned r = (u + 0x7FFF + ((u >> 16) & 1)) >> 16;   // RNE
    return (unsigned short)r;
}
static __device__ __forceinline__ float bf2f(unsigned short u) {
    return __uint_as_float(((unsigned)u) << 16);
}
static __device__ __forceinline__ float ldval(const float* p) { return *p; }
static __device__ __forceinline__ float ldval(const unsigned short* p) { return bf2f(*p); }

// ---------------------------------------------------------------------------
// zero ints
// ---------------------------------------------------------------------------
__global__ __launch_bounds__(256) void zero_int_kernel(int* __restrict__ p, int n) {
    int i = blockIdx.x * 256 + threadIdx.x;
    if (i < n) p[i] = 0;
}

// ---------------------------------------------------------------------------
// graph boundary search
// ---------------------------------------------------------------------------
__global__ __launch_bounds__(256) void find_starts_kernel(const int* __restrict__ batch,
                                                          int N, int G,
                                                          int* __restrict__ starts) {
    int g = blockIdx.x * 256 + threadIdx.x;
    if (g > G) return;
    if (g == G) { starts[G] = N; return; }
    int lo = 0, hi = N;
    while (lo < hi) {
        int mid = (lo + hi) >> 1;
        if (batch[mid] < g) lo = mid + 1; else hi = mid;
    }
    starts[g] = lo;
}

// ---------------------------------------------------------------------------
// CSR build: histogram, 3-phase multi-block scan, fill.
// (Previous single-block scan: 1 block on 256 CUs, serial 98-elem chains ->
//  234 us at 0.15% occupancy. 3-phase scan is fully grid-parallel.)
// ---------------------------------------------------------------------------
__global__ __launch_bounds__(256) void hist_kernel(const int* __restrict__ ei,
                                                   int E, int* __restrict__ deg) {
    int e = blockIdx.x * 256 + threadIdx.x;
    if (e >= E) return;
    atomicAdd(&deg[ei[E + e]], 1);
}

// phase 1: block-local exclusive scan of deg -> rowptr; block totals -> bsum
__global__ __launch_bounds__(256) void scan_phase1_kernel(const int* __restrict__ deg,
                                                          int N,
                                                          int* __restrict__ rowptr,
                                                          int* __restrict__ bsum) {
    __shared__ int sh[256];
    int t = threadIdx.x;
    int i = blockIdx.x * 256 + t;
    int v = (i < N) ? deg[i] : 0;
    sh[t] = v;
    __syncthreads();
    for (int offd = 1; offd < 256; offd <<= 1) {
        int add = (t >= offd) ? sh[t - offd] : 0;
        __syncthreads();
        sh[t] += add;
        __syncthreads();
    }
    if (i < N) rowptr[i] = sh[t] - v;   // exclusive
    if (t == 255) bsum[blockIdx.x] = sh[255];
}

// phase 2: single block scans bsum[NB] (NB <= 1024) -> exclusive block prefix
__global__ __launch_bounds__(1024) void scan_phase2_kernel(int* __restrict__ bsum, int NB) {
    __shared__ int sh[1024];
    int t = threadIdx.x;
    int v = (t < NB) ? bsum[t] : 0;
    sh[t] = v;
    __syncthreads();
    for (int offd = 1; offd < 1024; offd <<= 1) {
        int add = (t >= offd) ? sh[t - offd] : 0;
        __syncthreads();
        sh[t] += add;
        __syncthreads();
    }
    if (t < NB) bsum[t] = sh[t] - v;    // exclusive
}

// phase 3: add block prefix; write cursor; set rowptr[N]=E
__global__ __launch_bounds__(256) void scan_phase3_kernel(int* __restrict__ rowptr,
                                                          int* __restrict__ cursor,
                                                          const int* __restrict__ bsum,
                                                          int N, int E) {
    int i = blockIdx.x * 256 + threadIdx.x;
    if (i < N) {
        int r = rowptr[i] + bsum[blockIdx.x];
        rowptr[i] = r;
        cursor[i] = r;
    }
    if (blockIdx.x == 0 && threadIdx.x == 0) rowptr[N] = E;
}

__global__ __launch_bounds__(256) void fill_kernel(const int* __restrict__ ei,
                                                   int E,
                                                   int* __restrict__ cursor,
                                                   int* __restrict__ col) {
    int e = blockIdx.x * 256 + threadIdx.x;
    if (e >= E) return;
    int src = ei[e];
    int dst = ei[E + e];
    int pos = atomicAdd(&cursor[dst], 1);
    col[pos] = src;
}

// ---------------------------------------------------------------------------
// weight transpose+convert: Wt[c][k] (bf16, [CPAD][KP], zero-padded)
// ---------------------------------------------------------------------------
__global__ __launch_bounds__(128) void wt_prep_kernel(const float* __restrict__ W,
                                                      unsigned short* __restrict__ Wt,
                                                      int OCr, int Fr, int KP) {
    int c = blockIdx.x;
    int k = threadIdx.x;
    unsigned short v = 0;
    if (c < OCr && k < Fr) v = f2bf(W[(size_t)k * OCr + c]);
    Wt[(size_t)c * KP + k] = v;
}

// ---------------------------------------------------------------------------
// CSR gather-aggregate -> bf16 padded rows
// ---------------------------------------------------------------------------
template<typename TIN, int F, int FPAD, int KP>
__global__ __launch_bounds__(256) void gather_bf16_kernel(unsigned short* __restrict__ t,
                                                          const TIN* __restrict__ x,
                                                          int SIN,
                                                          const int* __restrict__ rowptr,
                                                          const int* __restrict__ col,
                                                          int N) {
    int node = blockIdx.x * blockDim.y + threadIdx.y;
    int f = threadIdx.x;
    if (node >= N) return;
    if (f >= F) { t[(size_t)node * KP + f] = 0; return; }
    int s = rowptr[node], e = rowptr[node + 1];
    float a0 = ldval(x + (size_t)node * SIN + f);
    float a1 = 0.f, a2 = 0.f, a3 = 0.f;
    int j = s;
    for (; j + 3 < e; j += 4) {
        int s0 = col[j], s1 = col[j + 1], s2 = col[j + 2], s3 = col[j + 3];
        a0 += ldval(x + (size_t)s0 * SIN + f);
        a1 += ldval(x + (size_t)s1 * SIN + f);
        a2 += ldval(x + (size_t)s2 * SIN + f);
        a3 += ldval(x + (size_t)s3 * SIN + f);
    }
    for (; j < e; ++j) a0 += ldval(x + (size_t)col[j] * SIN + f);
    t[(size_t)node * KP + f] = f2bf((a0 + a1) + (a2 + a3));
}

// ---------------------------------------------------------------------------
// conv1 via MFMA 16x16x32 bf16: y = relu(t @ W + b), y stored bf16 [N][KP]
// ---------------------------------------------------------------------------
template<int KP, int KS, int NT>
__global__ __launch_bounds__(256) void conv1_mfma_kernel(const unsigned short* __restrict__ t,
                                                         const unsigned short* __restrict__ Wt,
                                                         const float* __restrict__ bias,
                                                         unsigned short* __restrict__ y,
                                                         int NC, int N) {
    int wave = threadIdx.x >> 6, lane = threadIdx.x & 63;
    int quad = lane >> 4, l15 = lane & 15;
    int r0 = (blockIdx.x * 4 + wave) * 16;
    const short8 z8 = {0, 0, 0, 0, 0, 0, 0, 0};
    short8 a[KS];
    int arow = r0 + l15;
#pragma unroll
    for (int ks = 0; ks < KS; ++ks)
        a[ks] = (arow < N) ? *(const short8*)(t + (size_t)arow * KP + ks * 32 + quad * 8) : z8;
#pragma unroll
    for (int nt = 0; nt < NT; ++nt) {
        int colb = nt * 16 + l15;
        floatx4 c = {0.f, 0.f, 0.f, 0.f};
#pragma unroll
        for (int ks = 0; ks < KS; ++ks) {
            short8 b = *(const short8*)(Wt + (size_t)colb * KP + ks * 32 + quad * 8);
            c = __builtin_amdgcn_mfma_f32_16x16x32_bf16(a[ks], b, c, 0, 0, 0);
        }
        float bc = (colb < NC) ? bias[colb] : 0.f;
#pragma unroll
        for (int r = 0; r < 4; ++r) {
            int row = r0 + quad * 4 + r;
            if (row < N) {
                float o = fmaxf(c[r] + bc, 0.f);
                y[(size_t)row * KP + colb] = f2bf(o);
            }
        }
    }
}

// ---------------------------------------------------------------------------
// conv2 + relu + mean/max pool via MFMA, fused per graph. No LDS.
// ---------------------------------------------------------------------------
template<int KP, int KS>
__global__ __launch_bounds__(256) void conv2_pool_mfma_kernel(const unsigned short* __restrict__ t,
                                                              const unsigned short* __restrict__ Wt,
                                                              const float* __restrict__ bias,
                                                              const int* __restrict__ starts,
                                                              float* __restrict__ pooled,
                                                              int OC) {
    int wave = threadIdx.x >> 6, lane = threadIdx.x & 63;
    int quad = lane >> 4, l15 = lane & 15;
    int g = blockIdx.y;
    int cw0 = blockIdx.x * 256 + wave * 64;
    short8 bfr[4][KS];
    float bs[4];
#pragma unroll
    for (int ti = 0; ti < 4; ++ti) {
        int colb = cw0 + ti * 16 + l15;
#pragma unroll
        for (int ks = 0; ks < KS; ++ks)
            bfr[ti][ks] = *(const short8*)(Wt + (size_t)colb * KP + ks * 32 + quad * 8);
        bs[ti] = (colb < OC) ? bias[colb] : 0.f;
    }
    int s = starts[g], e = starts[g + 1];
    float sum[4] = {0.f, 0.f, 0.f, 0.f};
    float mx[4]  = {0.f, 0.f, 0.f, 0.f};
    const short8 z8 = {0, 0, 0, 0, 0, 0, 0, 0};
    for (int ns = s; ns < e; ns += 16) {
        short8 a[KS];
        int arow = ns + l15;
        bool av = arow < e;
#pragma unroll
        for (int ks = 0; ks < KS; ++ks)
            a[ks] = av ? *(const short8*)(t + (size_t)arow * KP + ks * 32 + quad * 8) : z8;
        int rbase = ns + quad * 4;
#pragma unroll
        for (int ti = 0; ti < 4; ++ti) {
            floatx4 c = {0.f, 0.f, 0.f, 0.f};
#pragma unroll
            for (int ks = 0; ks < KS; ++ks)
                c = __builtin_amdgcn_mfma_f32_16x16x32_bf16(a[ks], bfr[ti][ks], c, 0, 0, 0);
#pragma unroll
            for (int r = 0; r < 4; ++r) {
                float o = fmaxf(c[r] + bs[ti], 0.f);
                if (rbase + r < e) {
                    sum[ti] += o;
                    mx[ti] = fmaxf(mx[ti], o);
                }
            }
        }
    }
    int cnt = e - s;
    float rc = 1.f / (float)(cnt > 0 ? cnt : 1);
#pragma unroll
    for (int ti = 0; ti < 4; ++ti) {
        float sv = sum[ti], mv = mx[ti];
        sv += __shfl_down(sv, 32);
        mv = fmaxf(mv, __shfl_down(mv, 32));
        sv += __shfl_down(sv, 16);
        mv = fmaxf(mv, __shfl_down(mv, 16));
        if (lane < 16) {
            int colb = cw0 + ti * 16 + l15;
            if (colb < OC) {
                size_t base = (size_t)g * (size_t)(2 * OC);
                pooled[base + colb] = sv * rc;
                pooled[base + OC + colb] = mv;
            }
        }
    }
}

// ---------------------------------------------------------------------------
// split-K fp32 GEMM + reduce epilogue (MLP/head1)
// ---------------------------------------------------------------------------
__global__ __launch_bounds__(256) void gemm_splitk_kernel(const float* __restrict__ A,
                                                          const float* __restrict__ B,
                                                          float* __restrict__ Cpart,
                                                          int M, int N, int K, int KC) {
    __shared__ float As[16][68];
    __shared__ float Bs[16][64];
    int tid = threadIdx.x;
    int tx = tid & 15, ty = tid >> 4;
    int m0 = blockIdx.y * 64, n0 = blockIdx.x * 64;
    int ks = blockIdx.z * KC;
    int ke = ks + KC < K ? ks + KC : K;
    float acc[4][4] = {};
    for (int k0 = ks; k0 < ke; k0 += 16) {
#pragma unroll
        for (int i = 0; i < 4; ++i) {
            int lin = tid + i * 256;
            int m = lin >> 4, k = lin & 15;
            int gm = m0 + m, gk = k0 + k;
            As[k][m] = (gm < M && gk < ke) ? A[(size_t)gm * K + gk] : 0.f;
        }
#pragma unroll
        for (int i = 0; i < 4; ++i) {
            int lin = tid + i * 256;
            int n = lin & 63, k = lin >> 6;
            int gn = n0 + n, gk = k0 + k;
            Bs[k][n] = (gk < ke && gn < N) ? B[(size_t)gk * N + gn] : 0.f;
        }
        __syncthreads();
#pragma unroll
        for (int k = 0; k < 16; ++k) {
            float a[4], b[4];
#pragma unroll
            for (int i = 0; i < 4; ++i) a[i] = As[k][ty * 4 + i];
#pragma unroll
            for (int j = 0; j < 4; ++j) b[j] = Bs[k][tx * 4 + j];
#pragma unroll
            for (int i = 0; i < 4; ++i)
#pragma unroll
                for (int j = 0; j < 4; ++j)
                    acc[i][j] = fmaf(a[i], b[j], acc[i][j]);
        }
        __syncthreads();
    }
    size_t base = (size_t)blockIdx.z * M * N;
#pragma unroll
    for (int i = 0; i < 4; ++i) {
        int gm = m0 + ty * 4 + i;
        if (gm >= M) continue;
#pragma unroll
        for (int j = 0; j < 4; ++j) {
            int gn = n0 + tx * 4 + j;
            if (gn >= N) continue;
            Cpart[base + (size_t)gm * N + gn] = acc[i][j];
        }
    }
}

__global__ __launch_bounds__(256) void reduce_bias_kernel(const float* __restrict__ Cpart,
                                                          const float* __restrict__ bias,
                                                          float* __restrict__ C,
                                                          int MN, int Nmask, int S, int relu) {
    int i = blockIdx.x * 256 + threadIdx.x;
    if (i >= MN) return;
    float s = 0.f;
    for (int z = 0; z < S; ++z) s += Cpart[(size_t)z * MN + i];
    s += bias[i & Nmask];
    if (relu) s = fmaxf(s, 0.f);
    C[i] = s;
}

// ---------------------------------------------------------------------------
// head2: z[row][0..1] = h[row][0..255] @ w2[256][2] + b2. Wave per row.
// ---------------------------------------------------------------------------
__global__ __launch_bounds__(256) void head2_kernel(const float* __restrict__ h,
                                                    const float* __restrict__ w2,
                                                    const float* __restrict__ b2,
                                                    float* __restrict__ z, int M) {
    int wave = threadIdx.x >> 6, lane = threadIdx.x & 63;
    int row = blockIdx.x * 4 + wave;
    if (row >= M) return;
    float4 hv = *(const float4*)(h + (size_t)row * 256 + lane * 4);
    const float* wp = w2 + lane * 8;
    float s0 = hv.x * wp[0] + hv.y * wp[2] + hv.z * wp[4] + hv.w * wp[6];
    float s1 = hv.x * wp[1] + hv.y * wp[3] + hv.z * wp[5] + hv.w * wp[7];
#pragma unroll
    for (int offd = 32; offd >= 1; offd >>= 1) {
        s0 += __shfl_down(s0, offd);
        s1 += __shfl_down(s1, offd);
    }
    if (lane == 0) {
        z[(size_t)row * 2 + 0] = s0 + b2[0];
        z[(size_t)row * 2 + 1] = s1 + b2[1];
    }
}

// ---------------------------------------------------------------------------
// batchnorm stats + apply
// ---------------------------------------------------------------------------
__global__ __launch_bounds__(256) void bn_stats_kernel(const float* __restrict__ p,
                                                       int rows, int cols,
                                                       float* __restrict__ mean,
                                                       float* __restrict__ inv) {
    int c = blockIdx.x;
    float s = 0.f, s2 = 0.f;
    for (int r = threadIdx.x; r < rows; r += 256) {
        float v = p[(size_t)r * cols + c];
        s += v;
        s2 += v * v;
    }
    __shared__ float ls[256], ls2[256];
    ls[threadIdx.x] = s;
    ls2[threadIdx.x] = s2;
    __syncthreads();
    for (int st = 128; st > 0; st >>= 1) {
        if (threadIdx.x < st) {
            ls[threadIdx.x] += ls[threadIdx.x + st];
            ls2[threadIdx.x] += ls2[threadIdx.x + st];
        }
        __syncthreads();
    }
    if (threadIdx.x == 0) {
        float m = ls[0] / (float)rows;
        float var = ls2[0] / (float)rows - m * m;
        mean[c] = m;
        inv[c] = 1.f / sqrtf(var + BN_EPS);
    }
}

__global__ __launch_bounds__(256) void bn_apply_kernel(const float* __restrict__ p,
                                                       const float* __restrict__ gamma,
                                                       const float* __restrict__ beta,
                                                       const float* __restrict__ mean,
                                                       const float* __restrict__ inv,
                                                       float* __restrict__ outp,
                                                       int total, int cols) {
    int i = blockIdx.x * 256 + threadIdx.x;
    if (i >= total) return;
    int c = i & (cols - 1);
    outp[i] = gamma[c] * (p[i] - mean[c]) * inv[c] + beta[c];
}

// ---------------------------------------------------------------------------
// launch
// ---------------------------------------------------------------------------
static inline int ceildiv(int a, int b) { return (a + b - 1) / b; }

extern "C" void kernel_launch(void* const* d_in, const int* in_sizes, int n_in,
                              void* d_out, int out_size, void* d_ws, size_t ws_size,
                              hipStream_t stream) {
    const float* x0   = (const float*)d_in[0];
    const float* x1   = (const float*)d_in[1];
    const int*   ei0  = (const int*)d_in[2];
    const int*   ei1  = (const int*)d_in[3];
    const int*   bat0 = (const int*)d_in[4];
    const int*   bat1 = (const int*)d_in[5];
    const float* w_c1 = (const float*)d_in[6];
    const float* b_c1 = (const float*)d_in[7];
    const float* w_c2 = (const float*)d_in[8];
    const float* b_c2 = (const float*)d_in[9];
    const float* w_c3 = (const float*)d_in[10];
    const float* b_c3 = (const float*)d_in[11];
    const float* w_c4 = (const float*)d_in[12];
    const float* b_c4 = (const float*)d_in[13];
    const float* g0_w1 = (const float*)d_in[14];
    const float* g0_b1 = (const float*)d_in[15];
    const float* g0_w2 = (const float*)d_in[16];
    const float* g0_b2 = (const float*)d_in[17];
    const float* g0_bn_g = (const float*)d_in[18];
    const float* g0_bn_b = (const float*)d_in[19];
    const float* g1_w1 = (const float*)d_in[20];
    const float* g1_b1 = (const float*)d_in[21];
    const float* g1_w2 = (const float*)d_in[22];
    const float* g1_b2 = (const float*)d_in[23];
    const float* g1_bn_g = (const float*)d_in[24];
    const float* g1_bn_b = (const float*)d_in[25];
    const float* f0_w1 = (const float*)d_in[26];
    const float* f0_b1 = (const float*)d_in[27];
    const float* f0_w2 = (const float*)d_in[28];
    const float* f0_b2 = (const float*)d_in[29];
    const float* f1_w1 = (const float*)d_in[30];
    const float* f1_b1 = (const float*)d_in[31];
    const float* f1_w2 = (const float*)d_in[32];
    const float* f1_b2 = (const float*)d_in[33];

    float* out = (float*)d_out;
    float* out_z   = out;
    float* out_xg0 = out + 1024;
    float* out_xg1 = out + 1024 + 262144;
    float* out_z1  = out + 1024 + 262144 + 262144;

    // workspace carve (floats; all offsets multiples of 4 -> 16B aligned)
    float* ws = (float*)d_ws;
    size_t off = 0;
    auto alloc = [&](size_t n) { float* p = ws + off; off += n; return p; };
    unsigned short* t_bf = (unsigned short*)alloc((size_t)N0 * 96 / 2);  // bf16 [N][96]
    unsigned short* y_bf = (unsigned short*)alloc((size_t)N0 * 96 / 2);  // bf16 [N][96]
    unsigned short* wt_a = (unsigned short*)alloc(96 * 96 / 2);          // conv1 Wt
    unsigned short* wt_b = (unsigned short*)alloc(1024 * 96 / 2);        // conv2 Wt
    float* cpart = alloc((size_t)8 * 512 * 1024);                        // split-K partials
    int*   bsum  = (int*)alloc(512);                                     // scan block sums
    // Union region C: CSR (graph phase) aliases MLP temps (dense phase).
    size_t csr_floats = (size_t)N0 + (N0 + 1) + N0 + E0C;
    size_t mlp_floats = (size_t)GCONST * 2 * OC0 + (size_t)GCONST * 2 * OC1 +
                        (size_t)GCONST * 1024 + (size_t)GCONST * 512 +
                        (size_t)GCONST * 256;
    float* regionC = alloc(csr_floats > mlp_floats ? csr_floats : mlp_floats);
    int* deg    = (int*)regionC;
    int* rowptr = deg + N0;
    int* cursor = rowptr + (N0 + 1);
    int* colb   = cursor + N0;
    float* pooled0 = regionC;
    float* pooled1 = pooled0 + (size_t)GCONST * 2 * OC0;
    float* m1      = pooled1 + (size_t)GCONST * 2 * OC1;
    float* pbn     = m1 + (size_t)GCONST * 1024;
    float* hbuf    = pbn + (size_t)GCONST * 512;
    float* meanb   = alloc(512);
    float* invb    = alloc(512);
    int*   starts0 = (int*)alloc(520);
    int*   starts1 = (int*)alloc(520);

    const int G = GCONST;
    const int NB0 = ceildiv(N0, 256);   // 391 scan blocks (<= 1024)

    // =========================== branch 0 (F=93, KP=96) ===========================
    {
        const int N = N0, E = E0C, OC = OC0;
        find_starts_kernel<<<3, 256, 0, stream>>>(bat0, N, G, starts0);
        zero_int_kernel<<<ceildiv(N, 256), 256, 0, stream>>>(deg, N);
        hist_kernel<<<ceildiv(E, 256), 256, 0, stream>>>(ei0, E, deg);
        scan_phase1_kernel<<<NB0, 256, 0, stream>>>(deg, N, rowptr, bsum);
        scan_phase2_kernel<<<1, 1024, 0, stream>>>(bsum, NB0);
        scan_phase3_kernel<<<NB0, 256, 0, stream>>>(rowptr, cursor, bsum, N, E);
        fill_kernel<<<ceildiv(E, 256), 256, 0, stream>>>(ei0, E, cursor, colb);
        wt_prep_kernel<<<96, 96, 0, stream>>>(w_c1, wt_a, 93, 93, 96);
        wt_prep_kernel<<<1024, 96, 0, stream>>>(w_c2, wt_b, 930, 93, 96);
        gather_bf16_kernel<float, 93, 96, 96><<<ceildiv(N, 2), dim3(96, 2), 0, stream>>>(
            t_bf, x0, 93, rowptr, colb, N);
        conv1_mfma_kernel<96, 3, 6><<<ceildiv(N, 64), 256, 0, stream>>>(
            t_bf, wt_a, b_c1, y_bf, 93, N);
        gather_bf16_kernel<unsigned short, 93, 96, 96><<<ceildiv(N, 2), dim3(96, 2), 0, stream>>>(
            t_bf, y_bf, 96, rowptr, colb, N);
        conv2_pool_mfma_kernel<96, 3><<<dim3(4, G), 256, 0, stream>>>(
            t_bf, wt_b, b_c2, starts0, pooled0, OC);
        // MLP (fp32, split-K)
        gemm_splitk_kernel<<<dim3(16, 8, 8), 256, 0, stream>>>(
            pooled0, g0_w1, cpart, G, 1024, 2 * OC, 240);
        reduce_bias_kernel<<<ceildiv(G * 1024, 256), 256, 0, stream>>>(
            cpart, g0_b1, m1, G * 1024, 1023, 8, 1);
        gemm_splitk_kernel<<<dim3(8, 8, 8), 256, 0, stream>>>(
            m1, g0_w2, cpart, G, 512, 1024, 128);
        reduce_bias_kernel<<<ceildiv(G * 512, 256), 256, 0, stream>>>(
            cpart, g0_b2, pbn, G * 512, 511, 8, 0);
        bn_stats_kernel<<<512, 256, 0, stream>>>(pbn, G, 512, meanb, invb);
        bn_apply_kernel<<<ceildiv(G * 512, 256), 256, 0, stream>>>(
            pbn, g0_bn_g, g0_bn_b, meanb, invb, out_xg0, G * 512, 512);
        // head
        gemm_splitk_kernel<<<dim3(4, 8, 8), 256, 0, stream>>>(
            out_xg0, f0_w1, cpart, G, 256, 512, 64);
        reduce_bias_kernel<<<ceildiv(G * 256, 256), 256, 0, stream>>>(
            cpart, f0_b1, hbuf, G * 256, 255, 8, 1);
        head2_kernel<<<G / 4, 256, 0, stream>>>(hbuf, f0_w2, f0_b2, out_z, G);
    }

    // =========================== branch 1 (F=43, KP=64) ===========================
    {
        const int N = N1, E = E1C, OC = OC1;
        find_starts_kernel<<<3, 256, 0, stream>>>(bat1, N, G, starts1);
        zero_int_kernel<<<ceildiv(N, 256), 256, 0, stream>>>(deg, N);
        hist_kernel<<<ceildiv(E, 256), 256, 0, stream>>>(ei1, E, deg);
        scan_phase1_kernel<<<NB0, 256, 0, stream>>>(deg, N, rowptr, bsum);
        scan_phase2_kernel<<<1, 1024, 0, stream>>>(bsum, NB0);
        scan_phase3_kernel<<<NB0, 256, 0, stream>>>(rowptr, cursor, bsum, N, E);
        fill_kernel<<<ceildiv(E, 256), 256, 0, stream>>>(ei1, E, cursor, colb);
        wt_prep_kernel<<<48, 64, 0, stream>>>(w_c3, wt_a, 43, 43, 64);
        wt_prep_kernel<<<512, 64, 0, stream>>>(w_c4, wt_b, 430, 43, 64);
        gather_bf16_kernel<float, 43, 64, 64><<<ceildiv(N, 4), dim3(64, 4), 0, stream>>>(
            t_bf, x1, 43, rowptr, colb, N);
        conv1_mfma_kernel<64, 2, 3><<<ceildiv(N, 64), 256, 0, stream>>>(
            t_bf, wt_a, b_c3, y_bf, 43, N);
        gather_bf16_kernel<unsigned short, 43, 64, 64><<<ceildiv(N, 4), dim3(64, 4), 0, stream>>>(
            t_bf, y_bf, 64, rowptr, colb, N);
        conv2_pool_mfma_kernel<64, 2><<<dim3(2, G), 256, 0, stream>>>(
            t_bf, wt_b, b_c4, starts1, pooled1, OC);
        gemm_splitk_kernel<<<dim3(16, 8, 8), 256, 0, stream>>>(
            pooled1, g1_w1, cpart, G, 1024, 2 * OC, 112);
        reduce_bias_kernel<<<ceildiv(G * 1024, 256), 256, 0, stream>>>(
            cpart, g1_b1, m1, G * 1024, 1023, 8, 1);
        gemm_splitk_kernel<<<dim3(8, 8, 8), 256, 0, stream>>>(
            m1, g1_w2, cpart, G, 512, 1024, 128);
        reduce_bias_kernel<<<ceildiv(G * 512, 256), 256, 0, stream>>>(
            cpart, g1_b2, pbn, G * 512, 511, 8, 0);
        bn_stats_kernel<<<512, 256, 0, stream>>>(pbn, G, 512, meanb, invb);
        bn_apply_kernel<<<ceildiv(G * 512, 256), 256, 0, stream>>>(
            pbn, g1_bn_g, g1_bn_b, meanb, invb, out_xg1, G * 512, 512);
        gemm_splitk_kernel<<<dim3(4, 8, 8), 256, 0, stream>>>(
            out_xg1, f1_w1, cpart, G, 256, 512, 64);
        reduce_bias_kernel<<<ceildiv(G * 256, 256), 256, 0, stream>>>(
            cpart, f1_b1, hbuf, G * 256, 255, 8, 1);
        head2_kernel<<<G / 4, 256, 0, stream>>>(hbuf, f1_w2, f1_b2, out_z1, G);
    }
}

// Round 9
// 1076.004 us; speedup vs baseline: 3.2489x; 1.1484x over previous
//
#include <hip/hip_runtime.h>
#include <hip/hip_bf16.h>

// ---------------------------------------------------------------------------
// Problem constants
// ---------------------------------------------------------------------------
#define N0 100000
#define E0C 1600000
#define N1 100000
#define E1C 1600000
#define GCONST 512
#define F0C 93
#define F1C 43
#define OC0 (F0C * 10)   // 930
#define OC1 (F1C * 10)   // 430
#define BN_EPS 1e-5f
#define NBKT 391         // ceil(100000 / 256) buckets for CSR fill

typedef __attribute__((ext_vector_type(8))) short short8;
typedef __attribute__((ext_vector_type(4))) float floatx4;

static __device__ __forceinline__ unsigned short f2bf(float f) {
    unsigned u = __float_as_uint(f);
    unsigned r = (u + 0x7FFF + ((u >> 16) & 1)) >> 16;   // RNE
    return (unsigned short)r;
}
static __device__ __forceinline__ float bf2f(unsigned short u) {
    return __uint_as_float(((unsigned)u) << 16);
}
static __device__ __forceinline__ float ldval(const float* p) { return *p; }
static __device__ __forceinline__ float ldval(const unsigned short* p) { return bf2f(*p); }

// ---------------------------------------------------------------------------
// zero ints
// ---------------------------------------------------------------------------
__global__ __launch_bounds__(256) void zero_int_kernel(int* __restrict__ p, int n) {
    int i = blockIdx.x * 256 + threadIdx.x;
    if (i < n) p[i] = 0;
}

// ---------------------------------------------------------------------------
// graph boundary search
// ---------------------------------------------------------------------------
__global__ __launch_bounds__(256) void find_starts_kernel(const int* __restrict__ batch,
                                                          int N, int G,
                                                          int* __restrict__ starts) {
    int g = blockIdx.x * 256 + threadIdx.x;
    if (g > G) return;
    if (g == G) { starts[G] = N; return; }
    int lo = 0, hi = N;
    while (lo < hi) {
        int mid = (lo + hi) >> 1;
        if (batch[mid] < g) lo = mid + 1; else hi = mid;
    }
    starts[g] = lo;
}

// ---------------------------------------------------------------------------
// CSR build: histogram, 3-phase multi-block scan, two-phase bucketed fill.
// (Direct scattered fill: 100k hot cursors -> every 4B write cost a 64B line
//  writeback (WRITE_SIZE 105 MB for 6.4 MB payload, 134 us). Bucketed fill
//  keeps writes contiguous per (block,bucket) run / per-bucket region.)
// ---------------------------------------------------------------------------
__global__ __launch_bounds__(256) void hist_kernel(const int* __restrict__ ei,
                                                   int E, int* __restrict__ deg) {
    int e = blockIdx.x * 256 + threadIdx.x;
    if (e >= E) return;
    atomicAdd(&deg[ei[E + e]], 1);
}

// phase 1: block-local exclusive scan of deg -> rowptr; block totals -> bsum
__global__ __launch_bounds__(256) void scan_phase1_kernel(const int* __restrict__ deg,
                                                          int N,
                                                          int* __restrict__ rowptr,
                                                          int* __restrict__ bsum) {
    __shared__ int sh[256];
    int t = threadIdx.x;
    int i = blockIdx.x * 256 + t;
    int v = (i < N) ? deg[i] : 0;
    sh[t] = v;
    __syncthreads();
    for (int offd = 1; offd < 256; offd <<= 1) {
        int add = (t >= offd) ? sh[t - offd] : 0;
        __syncthreads();
        sh[t] += add;
        __syncthreads();
    }
    if (i < N) rowptr[i] = sh[t] - v;   // exclusive
    if (t == 255) bsum[blockIdx.x] = sh[255];
}

// phase 2: single block scans bsum[NB] (NB <= 1024) -> exclusive block prefix
__global__ __launch_bounds__(1024) void scan_phase2_kernel(int* __restrict__ bsum, int NB) {
    __shared__ int sh[1024];
    int t = threadIdx.x;
    int v = (t < NB) ? bsum[t] : 0;
    sh[t] = v;
    __syncthreads();
    for (int offd = 1; offd < 1024; offd <<= 1) {
        int add = (t >= offd) ? sh[t - offd] : 0;
        __syncthreads();
        sh[t] += add;
        __syncthreads();
    }
    if (t < NB) bsum[t] = sh[t] - v;    // exclusive
}

// phase 3: add block prefix; init bucket cursors (bcur[b] = rowptr[256b]);
// set rowptr[N]=E
__global__ __launch_bounds__(256) void scan_phase3_kernel(int* __restrict__ rowptr,
                                                          int* __restrict__ bcur,
                                                          const int* __restrict__ bsum,
                                                          int N, int E) {
    int i = blockIdx.x * 256 + threadIdx.x;
    if (i < N) {
        int r = rowptr[i] + bsum[blockIdx.x];
        rowptr[i] = r;
        if ((i & 255) == 0) bcur[i >> 8] = r;
    }
    if (blockIdx.x == 0 && threadIdx.x == 0) rowptr[N] = E;
}

// fill pass A: bucketize edges into staging (bucket = dst>>8). Block-local
// LDS histogram + one bulk global atomicAdd per (block,bucket) -> contiguous
// runs -> ~1x write amplification instead of 16x.
__global__ __launch_bounds__(256) void edge_bucket_kernel(const int* __restrict__ ei,
                                                          int E,
                                                          int* __restrict__ bcur,
                                                          int2* __restrict__ staging) {
    __shared__ int hist[NBKT];
    __shared__ int gbase[NBKT];
    int t = threadIdx.x;
    for (int i = t; i < NBKT; i += 256) hist[i] = 0;
    __syncthreads();
    int base = blockIdx.x * 2048;
    int srcv[8], dstv[8];
#pragma unroll
    for (int i = 0; i < 8; ++i) {
        int e = base + i * 256 + t;
        if (e < E) { srcv[i] = ei[e]; dstv[i] = ei[E + e]; }
        else dstv[i] = -1;
    }
#pragma unroll
    for (int i = 0; i < 8; ++i)
        if (dstv[i] >= 0) atomicAdd(&hist[dstv[i] >> 8], 1);
    __syncthreads();
    for (int i = t; i < NBKT; i += 256) {
        int c = hist[i];
        gbase[i] = c ? atomicAdd(&bcur[i], c) : 0;
        hist[i] = 0;   // reuse as local cursor
    }
    __syncthreads();
#pragma unroll
    for (int i = 0; i < 8; ++i) {
        if (dstv[i] >= 0) {
            int b = dstv[i] >> 8;
            int lofs = atomicAdd(&hist[b], 1);
            staging[gbase[b] + lofs] = make_int2(srcv[i], dstv[i]);
        }
    }
}

// fill pass B: block per bucket; LDS node cursors; scatter col within the
// bucket's contiguous ~16KB region (all writes from one CU -> lines fill).
__global__ __launch_bounds__(256) void csr_fill_kernel(const int2* __restrict__ staging,
                                                       const int* __restrict__ rowptr,
                                                       int N, int E,
                                                       int* __restrict__ col) {
    __shared__ int lcur[256];
    int b = blockIdx.x;
    int n0 = b << 8;
    int t = threadIdx.x;
    int node = n0 + t;
    lcur[t] = (node < N) ? rowptr[node] : 0;
    __syncthreads();
    int estart = rowptr[n0];
    int nend = (n0 + 256 < N) ? n0 + 256 : N;
    int eend = rowptr[nend];
    for (int e = estart + t; e < eend; e += 256) {
        int2 ed = staging[e];
        int pos = atomicAdd(&lcur[ed.y - n0], 1);
        col[pos] = ed.x;
    }
}

// ---------------------------------------------------------------------------
// weight transpose+convert: Wt[c][k] (bf16, [CPAD][KP], zero-padded)
// ---------------------------------------------------------------------------
__global__ __launch_bounds__(128) void wt_prep_kernel(const float* __restrict__ W,
                                                      unsigned short* __restrict__ Wt,
                                                      int OCr, int Fr, int KP) {
    int c = blockIdx.x;
    int k = threadIdx.x;
    unsigned short v = 0;
    if (c < OCr && k < Fr) v = f2bf(W[(size_t)k * OCr + c]);
    Wt[(size_t)c * KP + k] = v;
}

// ---------------------------------------------------------------------------
// CSR gather-aggregate -> bf16 padded rows
// ---------------------------------------------------------------------------
template<typename TIN, int F, int FPAD, int KP>
__global__ __launch_bounds__(256) void gather_bf16_kernel(unsigned short* __restrict__ t,
                                                          const TIN* __restrict__ x,
                                                          int SIN,
                                                          const int* __restrict__ rowptr,
                                                          const int* __restrict__ col,
                                                          int N) {
    int node = blockIdx.x * blockDim.y + threadIdx.y;
    int f = threadIdx.x;
    if (node >= N) return;
    if (f >= F) { t[(size_t)node * KP + f] = 0; return; }
    int s = rowptr[node], e = rowptr[node + 1];
    float a0 = ldval(x + (size_t)node * SIN + f);
    float a1 = 0.f, a2 = 0.f, a3 = 0.f;
    int j = s;
    for (; j + 3 < e; j += 4) {
        int s0 = col[j], s1 = col[j + 1], s2 = col[j + 2], s3 = col[j + 3];
        a0 += ldval(x + (size_t)s0 * SIN + f);
        a1 += ldval(x + (size_t)s1 * SIN + f);
        a2 += ldval(x + (size_t)s2 * SIN + f);
        a3 += ldval(x + (size_t)s3 * SIN + f);
    }
    for (; j < e; ++j) a0 += ldval(x + (size_t)col[j] * SIN + f);
    t[(size_t)node * KP + f] = f2bf((a0 + a1) + (a2 + a3));
}

// ---------------------------------------------------------------------------
// conv1 via MFMA 16x16x32 bf16: y = relu(t @ W + b), y stored bf16 [N][KP]
// ---------------------------------------------------------------------------
template<int KP, int KS, int NT>
__global__ __launch_bounds__(256) void conv1_mfma_kernel(const unsigned short* __restrict__ t,
                                                         const unsigned short* __restrict__ Wt,
                                                         const float* __restrict__ bias,
                                                         unsigned short* __restrict__ y,
                                                         int NC, int N) {
    int wave = threadIdx.x >> 6, lane = threadIdx.x & 63;
    int quad = lane >> 4, l15 = lane & 15;
    int r0 = (blockIdx.x * 4 + wave) * 16;
    const short8 z8 = {0, 0, 0, 0, 0, 0, 0, 0};
    short8 a[KS];
    int arow = r0 + l15;
#pragma unroll
    for (int ks = 0; ks < KS; ++ks)
        a[ks] = (arow < N) ? *(const short8*)(t + (size_t)arow * KP + ks * 32 + quad * 8) : z8;
#pragma unroll
    for (int nt = 0; nt < NT; ++nt) {
        int colb = nt * 16 + l15;
        floatx4 c = {0.f, 0.f, 0.f, 0.f};
#pragma unroll
        for (int ks = 0; ks < KS; ++ks) {
            short8 b = *(const short8*)(Wt + (size_t)colb * KP + ks * 32 + quad * 8);
            c = __builtin_amdgcn_mfma_f32_16x16x32_bf16(a[ks], b, c, 0, 0, 0);
        }
        float bc = (colb < NC) ? bias[colb] : 0.f;
#pragma unroll
        for (int r = 0; r < 4; ++r) {
            int row = r0 + quad * 4 + r;
            if (row < N) {
                float o = fmaxf(c[r] + bc, 0.f);
                y[(size_t)row * KP + colb] = f2bf(o);
            }
        }
    }
}

// ---------------------------------------------------------------------------
// conv2 + relu + mean/max pool via MFMA, fused per graph. No LDS.
// ---------------------------------------------------------------------------
template<int KP, int KS>
__global__ __launch_bounds__(256) void conv2_pool_mfma_kernel(const unsigned short* __restrict__ t,
                                                              const unsigned short* __restrict__ Wt,
                                                              const float* __restrict__ bias,
                                                              const int* __restrict__ starts,
                                                              float* __restrict__ pooled,
                                                              int OC) {
    int wave = threadIdx.x >> 6, lane = threadIdx.x & 63;
    int quad = lane >> 4, l15 = lane & 15;
    int g = blockIdx.y;
    int cw0 = blockIdx.x * 256 + wave * 64;
    short8 bfr[4][KS];
    float bs[4];
#pragma unroll
    for (int ti = 0; ti < 4; ++ti) {
        int colb = cw0 + ti * 16 + l15;
#pragma unroll
        for (int ks = 0; ks < KS; ++ks)
            bfr[ti][ks] = *(const short8*)(Wt + (size_t)colb * KP + ks * 32 + quad * 8);
        bs[ti] = (colb < OC) ? bias[colb] : 0.f;
    }
    int s = starts[g], e = starts[g + 1];
    float sum[4] = {0.f, 0.f, 0.f, 0.f};
    float mx[4]  = {0.f, 0.f, 0.f, 0.f};
    const short8 z8 = {0, 0, 0, 0, 0, 0, 0, 0};
    for (int ns = s; ns < e; ns += 16) {
        short8 a[KS];
        int arow = ns + l15;
        bool av = arow < e;
#pragma unroll
        for (int ks = 0; ks < KS; ++ks)
            a[ks] = av ? *(const short8*)(t + (size_t)arow * KP + ks * 32 + quad * 8) : z8;
        int rbase = ns + quad * 4;
#pragma unroll
        for (int ti = 0; ti < 4; ++ti) {
            floatx4 c = {0.f, 0.f, 0.f, 0.f};
#pragma unroll
            for (int ks = 0; ks < KS; ++ks)
                c = __builtin_amdgcn_mfma_f32_16x16x32_bf16(a[ks], bfr[ti][ks], c, 0, 0, 0);
#pragma unroll
            for (int r = 0; r < 4; ++r) {
                float o = fmaxf(c[r] + bs[ti], 0.f);
                if (rbase + r < e) {
                    sum[ti] += o;
                    mx[ti] = fmaxf(mx[ti], o);
                }
            }
        }
    }
    int cnt = e - s;
    float rc = 1.f / (float)(cnt > 0 ? cnt : 1);
#pragma unroll
    for (int ti = 0; ti < 4; ++ti) {
        float sv = sum[ti], mv = mx[ti];
        sv += __shfl_down(sv, 32);
        mv = fmaxf(mv, __shfl_down(mv, 32));
        sv += __shfl_down(sv, 16);
        mv = fmaxf(mv, __shfl_down(mv, 16));
        if (lane < 16) {
            int colb = cw0 + ti * 16 + l15;
            if (colb < OC) {
                size_t base = (size_t)g * (size_t)(2 * OC);
                pooled[base + colb] = sv * rc;
                pooled[base + OC + colb] = mv;
            }
        }
    }
}

// ---------------------------------------------------------------------------
// split-K fp32 GEMM + reduce epilogue (MLP/head1)
// ---------------------------------------------------------------------------
__global__ __launch_bounds__(256) void gemm_splitk_kernel(const float* __restrict__ A,
                                                          const float* __restrict__ B,
                                                          float* __restrict__ Cpart,
                                                          int M, int N, int K, int KC) {
    __shared__ float As[16][68];
    __shared__ float Bs[16][64];
    int tid = threadIdx.x;
    int tx = tid & 15, ty = tid >> 4;
    int m0 = blockIdx.y * 64, n0 = blockIdx.x * 64;
    int ks = blockIdx.z * KC;
    int ke = ks + KC < K ? ks + KC : K;
    float acc[4][4] = {};
    for (int k0 = ks; k0 < ke; k0 += 16) {
#pragma unroll
        for (int i = 0; i < 4; ++i) {
            int lin = tid + i * 256;
            int m = lin >> 4, k = lin & 15;
            int gm = m0 + m, gk = k0 + k;
            As[k][m] = (gm < M && gk < ke) ? A[(size_t)gm * K + gk] : 0.f;
        }
#pragma unroll
        for (int i = 0; i < 4; ++i) {
            int lin = tid + i * 256;
            int n = lin & 63, k = lin >> 6;
            int gn = n0 + n, gk = k0 + k;
            Bs[k][n] = (gk < ke && gn < N) ? B[(size_t)gk * N + gn] : 0.f;
        }
        __syncthreads();
#pragma unroll
        for (int k = 0; k < 16; ++k) {
            float a[4], b[4];
#pragma unroll
            for (int i = 0; i < 4; ++i) a[i] = As[k][ty * 4 + i];
#pragma unroll
            for (int j = 0; j < 4; ++j) b[j] = Bs[k][tx * 4 + j];
#pragma unroll
            for (int i = 0; i < 4; ++i)
#pragma unroll
                for (int j = 0; j < 4; ++j)
                    acc[i][j] = fmaf(a[i], b[j], acc[i][j]);
        }
        __syncthreads();
    }
    size_t base = (size_t)blockIdx.z * M * N;
#pragma unroll
    for (int i = 0; i < 4; ++i) {
        int gm = m0 + ty * 4 + i;
        if (gm >= M) continue;
#pragma unroll
        for (int j = 0; j < 4; ++j) {
            int gn = n0 + tx * 4 + j;
            if (gn >= N) continue;
            Cpart[base + (size_t)gm * N + gn] = acc[i][j];
        }
    }
}

__global__ __launch_bounds__(256) void reduce_bias_kernel(const float* __restrict__ Cpart,
                                                          const float* __restrict__ bias,
                                                          float* __restrict__ C,
                                                          int MN, int Nmask, int S, int relu) {
    int i = blockIdx.x * 256 + threadIdx.x;
    if (i >= MN) return;
    float s = 0.f;
    for (int z = 0; z < S; ++z) s += Cpart[(size_t)z * MN + i];
    s += bias[i & Nmask];
    if (relu) s = fmaxf(s, 0.f);
    C[i] = s;
}

// ---------------------------------------------------------------------------
// head2: z[row][0..1] = h[row][0..255] @ w2[256][2] + b2. Wave per row.
// ---------------------------------------------------------------------------
__global__ __launch_bounds__(256) void head2_kernel(const float* __restrict__ h,
                                                    const float* __restrict__ w2,
                                                    const float* __restrict__ b2,
                                                    float* __restrict__ z, int M) {
    int wave = threadIdx.x >> 6, lane = threadIdx.x & 63;
    int row = blockIdx.x * 4 + wave;
    if (row >= M) return;
    float4 hv = *(const float4*)(h + (size_t)row * 256 + lane * 4);
    const float* wp = w2 + lane * 8;
    float s0 = hv.x * wp[0] + hv.y * wp[2] + hv.z * wp[4] + hv.w * wp[6];
    float s1 = hv.x * wp[1] + hv.y * wp[3] + hv.z * wp[5] + hv.w * wp[7];
#pragma unroll
    for (int offd = 32; offd >= 1; offd >>= 1) {
        s0 += __shfl_down(s0, offd);
        s1 += __shfl_down(s1, offd);
    }
    if (lane == 0) {
        z[(size_t)row * 2 + 0] = s0 + b2[0];
        z[(size_t)row * 2 + 1] = s1 + b2[1];
    }
}

// ---------------------------------------------------------------------------
// batchnorm stats + apply
// ---------------------------------------------------------------------------
__global__ __launch_bounds__(256) void bn_stats_kernel(const float* __restrict__ p,
                                                       int rows, int cols,
                                                       float* __restrict__ mean,
                                                       float* __restrict__ inv) {
    int c = blockIdx.x;
    float s = 0.f, s2 = 0.f;
    for (int r = threadIdx.x; r < rows; r += 256) {
        float v = p[(size_t)r * cols + c];
        s += v;
        s2 += v * v;
    }
    __shared__ float ls[256], ls2[256];
    ls[threadIdx.x] = s;
    ls2[threadIdx.x] = s2;
    __syncthreads();
    for (int st = 128; st > 0; st >>= 1) {
        if (threadIdx.x < st) {
            ls[threadIdx.x] += ls[threadIdx.x + st];
            ls2[threadIdx.x] += ls2[threadIdx.x + st];
        }
        __syncthreads();
    }
    if (threadIdx.x == 0) {
        float m = ls[0] / (float)rows;
        float var = ls2[0] / (float)rows - m * m;
        mean[c] = m;
        inv[c] = 1.f / sqrtf(var + BN_EPS);
    }
}

__global__ __launch_bounds__(256) void bn_apply_kernel(const float* __restrict__ p,
                                                       const float* __restrict__ gamma,
                                                       const float* __restrict__ beta,
                                                       const float* __restrict__ mean,
                                                       const float* __restrict__ inv,
                                                       float* __restrict__ outp,
                                                       int total, int cols) {
    int i = blockIdx.x * 256 + threadIdx.x;
    if (i >= total) return;
    int c = i & (cols - 1);
    outp[i] = gamma[c] * (p[i] - mean[c]) * inv[c] + beta[c];
}

// ---------------------------------------------------------------------------
// launch
// ---------------------------------------------------------------------------
static inline int ceildiv(int a, int b) { return (a + b - 1) / b; }

extern "C" void kernel_launch(void* const* d_in, const int* in_sizes, int n_in,
                              void* d_out, int out_size, void* d_ws, size_t ws_size,
                              hipStream_t stream) {
    const float* x0   = (const float*)d_in[0];
    const float* x1   = (const float*)d_in[1];
    const int*   ei0  = (const int*)d_in[2];
    const int*   ei1  = (const int*)d_in[3];
    const int*   bat0 = (const int*)d_in[4];
    const int*   bat1 = (const int*)d_in[5];
    const float* w_c1 = (const float*)d_in[6];
    const float* b_c1 = (const float*)d_in[7];
    const float* w_c2 = (const float*)d_in[8];
    const float* b_c2 = (const float*)d_in[9];
    const float* w_c3 = (const float*)d_in[10];
    const float* b_c3 = (const float*)d_in[11];
    const float* w_c4 = (const float*)d_in[12];
    const float* b_c4 = (const float*)d_in[13];
    const float* g0_w1 = (const float*)d_in[14];
    const float* g0_b1 = (const float*)d_in[15];
    const float* g0_w2 = (const float*)d_in[16];
    const float* g0_b2 = (const float*)d_in[17];
    const float* g0_bn_g = (const float*)d_in[18];
    const float* g0_bn_b = (const float*)d_in[19];
    const float* g1_w1 = (const float*)d_in[20];
    const float* g1_b1 = (const float*)d_in[21];
    const float* g1_w2 = (const float*)d_in[22];
    const float* g1_b2 = (const float*)d_in[23];
    const float* g1_bn_g = (const float*)d_in[24];
    const float* g1_bn_b = (const float*)d_in[25];
    const float* f0_w1 = (const float*)d_in[26];
    const float* f0_b1 = (const float*)d_in[27];
    const float* f0_w2 = (const float*)d_in[28];
    const float* f0_b2 = (const float*)d_in[29];
    const float* f1_w1 = (const float*)d_in[30];
    const float* f1_b1 = (const float*)d_in[31];
    const float* f1_w2 = (const float*)d_in[32];
    const float* f1_b2 = (const float*)d_in[33];

    float* out = (float*)d_out;
    float* out_z   = out;
    float* out_xg0 = out + 1024;
    float* out_xg1 = out + 1024 + 262144;
    float* out_z1  = out + 1024 + 262144 + 262144;

    // workspace carve (floats; all offsets multiples of 4 -> 16B aligned)
    float* ws = (float*)d_ws;
    size_t off = 0;
    auto alloc = [&](size_t n) { float* p = ws + off; off += n; return p; };
    unsigned short* t_bf = (unsigned short*)alloc((size_t)N0 * 96 / 2);  // bf16 [N][96]
    unsigned short* y_bf = (unsigned short*)alloc((size_t)N0 * 96 / 2);  // bf16 [N][96]
    unsigned short* wt_a = (unsigned short*)alloc(96 * 96 / 2);          // conv1 Wt
    unsigned short* wt_b = (unsigned short*)alloc(1024 * 96 / 2);        // conv2 Wt
    float* cpart = alloc((size_t)8 * 512 * 1024);                        // split-K partials
    int*   bsum  = (int*)alloc(512);                                     // scan block sums
    int*   bcur  = (int*)alloc(512);                                     // bucket cursors
    // Union region C: CSR (graph phase) aliases MLP temps (dense phase).
    size_t csr_floats = (size_t)N0 + (N0 + 4) + E0C + 2 * (size_t)E0C;   // deg|rowptr|col|staging
    size_t mlp_floats = (size_t)GCONST * 2 * OC0 + (size_t)GCONST * 2 * OC1 +
                        (size_t)GCONST * 1024 + (size_t)GCONST * 512 +
                        (size_t)GCONST * 256;
    float* regionC = alloc(csr_floats > mlp_floats ? csr_floats : mlp_floats);
    int* deg     = (int*)regionC;
    int* rowptr  = deg + N0;
    int* colb    = rowptr + (N0 + 4);
    int2* staging = (int2*)(colb + E0C);
    float* pooled0 = regionC;
    float* pooled1 = pooled0 + (size_t)GCONST * 2 * OC0;
    float* m1      = pooled1 + (size_t)GCONST * 2 * OC1;
    float* pbn     = m1 + (size_t)GCONST * 1024;
    float* hbuf    = pbn + (size_t)GCONST * 512;
    float* meanb   = alloc(512);
    float* invb    = alloc(512);
    int*   starts0 = (int*)alloc(520);
    int*   starts1 = (int*)alloc(520);

    const int G = GCONST;
    const int NBS = ceildiv(N0, 256);   // 391 scan blocks == NBKT buckets

    // =========================== branch 0 (F=93, KP=96) ===========================
    {
        const int N = N0, E = E0C, OC = OC0;
        find_starts_kernel<<<3, 256, 0, stream>>>(bat0, N, G, starts0);
        zero_int_kernel<<<ceildiv(N, 256), 256, 0, stream>>>(deg, N);
        hist_kernel<<<ceildiv(E, 256), 256, 0, stream>>>(ei0, E, deg);
        scan_phase1_kernel<<<NBS, 256, 0, stream>>>(deg, N, rowptr, bsum);
        scan_phase2_kernel<<<1, 1024, 0, stream>>>(bsum, NBS);
        scan_phase3_kernel<<<NBS, 256, 0, stream>>>(rowptr, bcur, bsum, N, E);
        edge_bucket_kernel<<<ceildiv(E, 2048), 256, 0, stream>>>(ei0, E, bcur, staging);
        csr_fill_kernel<<<NBKT, 256, 0, stream>>>(staging, rowptr, N, E, colb);
        wt_prep_kernel<<<96, 96, 0, stream>>>(w_c1, wt_a, 93, 93, 96);
        wt_prep_kernel<<<1024, 96, 0, stream>>>(w_c2, wt_b, 930, 93, 96);
        gather_bf16_kernel<float, 93, 96, 96><<<ceildiv(N, 2), dim3(96, 2), 0, stream>>>(
            t_bf, x0, 93, rowptr, colb, N);
        conv1_mfma_kernel<96, 3, 6><<<ceildiv(N, 64), 256, 0, stream>>>(
            t_bf, wt_a, b_c1, y_bf, 93, N);
        gather_bf16_kernel<unsigned short, 93, 96, 96><<<ceildiv(N, 2), dim3(96, 2), 0, stream>>>(
            t_bf, y_bf, 96, rowptr, colb, N);
        conv2_pool_mfma_kernel<96, 3><<<dim3(4, G), 256, 0, stream>>>(
            t_bf, wt_b, b_c2, starts0, pooled0, OC);
        // MLP (fp32, split-K)
        gemm_splitk_kernel<<<dim3(16, 8, 8), 256, 0, stream>>>(
            pooled0, g0_w1, cpart, G, 1024, 2 * OC, 240);
        reduce_bias_kernel<<<ceildiv(G * 1024, 256), 256, 0, stream>>>(
            cpart, g0_b1, m1, G * 1024, 1023, 8, 1);
        gemm_splitk_kernel<<<dim3(8, 8, 8), 256, 0, stream>>>(
            m1, g0_w2, cpart, G, 512, 1024, 128);
        reduce_bias_kernel<<<ceildiv(G * 512, 256), 256, 0, stream>>>(
            cpart, g0_b2, pbn, G * 512, 511, 8, 0);
        bn_stats_kernel<<<512, 256, 0, stream>>>(pbn, G, 512, meanb, invb);
        bn_apply_kernel<<<ceildiv(G * 512, 256), 256, 0, stream>>>(
            pbn, g0_bn_g, g0_bn_b, meanb, invb, out_xg0, G * 512, 512);
        // head
        gemm_splitk_kernel<<<dim3(4, 8, 8), 256, 0, stream>>>(
            out_xg0, f0_w1, cpart, G, 256, 512, 64);
        reduce_bias_kernel<<<ceildiv(G * 256, 256), 256, 0, stream>>>(
            cpart, f0_b1, hbuf, G * 256, 255, 8, 1);
        head2_kernel<<<G / 4, 256, 0, stream>>>(hbuf, f0_w2, f0_b2, out_z, G);
    }

    // =========================== branch 1 (F=43, KP=64) ===========================
    {
        const int N = N1, E = E1C, OC = OC1;
        find_starts_kernel<<<3, 256, 0, stream>>>(bat1, N, G, starts1);
        zero_int_kernel<<<ceildiv(N, 256), 256, 0, stream>>>(deg, N);
        hist_kernel<<<ceildiv(E, 256), 256, 0, stream>>>(ei1, E, deg);
        scan_phase1_kernel<<<NBS, 256, 0, stream>>>(deg, N, rowptr, bsum);
        scan_phase2_kernel<<<1, 1024, 0, stream>>>(bsum, NBS);
        scan_phase3_kernel<<<NBS, 256, 0, stream>>>(rowptr, bcur, bsum, N, E);
        edge_bucket_kernel<<<ceildiv(E, 2048), 256, 0, stream>>>(ei1, E, bcur, staging);
        csr_fill_kernel<<<NBKT, 256, 0, stream>>>(staging, rowptr, N, E, colb);
        wt_prep_kernel<<<48, 64, 0, stream>>>(w_c3, wt_a, 43, 43, 64);
        wt_prep_kernel<<<512, 64, 0, stream>>>(w_c4, wt_b, 430, 43, 64);
        gather_bf16_kernel<float, 43, 64, 64><<<ceildiv(N, 4), dim3(64, 4), 0, stream>>>(
            t_bf, x1, 43, rowptr, colb, N);
        conv1_mfma_kernel<64, 2, 3><<<ceildiv(N, 64), 256, 0, stream>>>(
            t_bf, wt_a, b_c3, y_bf, 43, N);
        gather_bf16_kernel<unsigned short, 43, 64, 64><<<ceildiv(N, 4), dim3(64, 4), 0, stream>>>(
            t_bf, y_bf, 64, rowptr, colb, N);
        conv2_pool_mfma_kernel<64, 2><<<dim3(2, G), 256, 0, stream>>>(
            t_bf, wt_b, b_c4, starts1, pooled1, OC);
        gemm_splitk_kernel<<<dim3(16, 8, 8), 256, 0, stream>>>(
            pooled1, g1_w1, cpart, G, 1024, 2 * OC, 112);
        reduce_bias_kernel<<<ceildiv(G * 1024, 256), 256, 0, stream>>>(
            cpart, g1_b1, m1, G * 1024, 1023, 8, 1);
        gemm_splitk_kernel<<<dim3(8, 8, 8), 256, 0, stream>>>(
            m1, g1_w2, cpart, G, 512, 1024, 128);
        reduce_bias_kernel<<<ceildiv(G * 512, 256), 256, 0, stream>>>(
            cpart, g1_b2, pbn, G * 512, 511, 8, 0);
        bn_stats_kernel<<<512, 256, 0, stream>>>(pbn, G, 512, meanb, invb);
        bn_apply_kernel<<<ceildiv(G * 512, 256), 256, 0, stream>>>(
            pbn, g1_bn_g, g1_bn_b, meanb, invb, out_xg1, G * 512, 512);
        gemm_splitk_kernel<<<dim3(4, 8, 8), 256, 0, stream>>>(
            out_xg1, f1_w1, cpart, G, 256, 512, 64);
        reduce_bias_kernel<<<ceildiv(G * 256, 256), 256, 0, stream>>>(
            cpart, f1_b1, hbuf, G * 256, 255, 8, 1);
        head2_kernel<<<G / 4, 256, 0, stream>>>(hbuf, f1_w2, f1_b2, out_z1, G);
    }
}